// Round 16
// baseline (259.984 us; speedup 1.0000x reference)
//
#include <hip/hip_runtime.h>
#include <cstdint>
#include <cstddef>

typedef __attribute__((ext_vector_type(8))) short short8;
typedef __attribute__((ext_vector_type(4))) float f32x4;
typedef unsigned short u16;

#define MFMA16(a, b, c) __builtin_amdgcn_mfma_f32_16x16x32_bf16((a), (b), (c), 0, 0, 0)
#define SCL2 0.18033688011112042f   /* 0.125 * log2(e) */

__device__ __forceinline__ u16 f2bf(float f) {
  union { float f; unsigned u; } c; c.f = f;
  unsigned r = c.u + 0x7fffu + ((c.u >> 16) & 1u);
  return (u16)(r >> 16);
}

__device__ __forceinline__ float bf2f(u16 x) {
  union { unsigned u; float f; } c; c.u = ((unsigned)x) << 16;
  return c.f;
}

__device__ __forceinline__ unsigned cvtpk(float a, float b) {
  unsigned r;
  asm("v_cvt_pk_bf16_f32 %0, %1, %2" : "=v"(r) : "v"(a), "v"(b));
  return r;
}

// ---------------------------------------------------------------------------
// Weight prep kernels (run every call; stateless)
// ---------------------------------------------------------------------------

__global__ __launch_bounds__(256) void prep_wqkv(const float* __restrict__ wq,
    const float* __restrict__ wk, const float* __restrict__ wv, u16* __restrict__ outp)
{
  __shared__ float t[32][33];
  const int tx = threadIdx.x & 31, ty = threadIdx.x >> 5;
  const int n0 = blockIdx.x * 32, d0 = blockIdx.y * 32;
  const float* src; int stride, nc;
  if (n0 < 1024)      { src = wq; stride = 1024; nc = n0; }
  else if (n0 < 1536) { src = wk; stride = 512;  nc = n0 - 1024; }
  else                { src = wv; stride = 512;  nc = n0 - 1536; }
#pragma unroll
  for (int i = 0; i < 32; i += 8)
    t[ty + i][tx] = src[(size_t)(d0 + ty + i) * stride + nc + tx];
  __syncthreads();
#pragma unroll
  for (int i = 0; i < 32; i += 8)
    outp[(size_t)(n0 + ty + i) * 1024 + d0 + tx] = f2bf(t[tx][ty + i]);
}

__global__ __launch_bounds__(256) void prep_wout(const float* __restrict__ wo, u16* __restrict__ outp)
{
  __shared__ float t[32][33];
  const int tx = threadIdx.x & 31, ty = threadIdx.x >> 5;
  const int d0 = blockIdx.x * 32, c0 = blockIdx.y * 32;
#pragma unroll
  for (int i = 0; i < 32; i += 8) {
    int c = c0 + ty + i;
    t[ty + i][tx] = wo[(size_t)(c & 63) * 16384 + (size_t)(c >> 6) * 1024 + d0 + tx];
  }
  __syncthreads();
#pragma unroll
  for (int i = 0; i < 32; i += 8)
    outp[(size_t)(d0 + ty + i) * 1024 + c0 + tx] = f2bf(t[tx][ty + i]);
}

__global__ void convert_bf16(const float4* __restrict__ in, u16* __restrict__ out, int n4) {
  int i = blockIdx.x * 256 + threadIdx.x;
  if (i >= n4) return;
  float4 v = in[i];
  ushort4 o; o.x = f2bf(v.x); o.y = f2bf(v.y); o.z = f2bf(v.z); o.w = f2bf(v.w);
  ((ushort4*)out)[i] = o;
}

// Vt[b][g][k][t] from qkv cols 1536+g*64+k
__global__ __launch_bounds__(256) void vt_transpose(const u16* __restrict__ qkv, u16* __restrict__ vtp)
{
  __shared__ u16 t[32][33];
  const int tx = threadIdx.x & 31, ty = threadIdx.x >> 5;
  const int t0 = blockIdx.x * 32, k0 = blockIdx.y * 32;
  const int bg = blockIdx.z, b = bg >> 3, g = bg & 7;
#pragma unroll
  for (int i = 0; i < 32; i += 8)
    t[ty + i][tx] = qkv[(size_t)(b * 2048 + t0 + ty + i) * 2048 + 1536 + g * 64 + k0 + tx];
  __syncthreads();
#pragma unroll
  for (int i = 0; i < 32; i += 8)
    vtp[(size_t)(bg * 64 + k0 + ty + i) * 2048 + t0 + tx] = t[tx][ty + i];
}

// ---------------------------------------------------------------------------
// LayerNorm (fp32 in -> bf16 out)
// ---------------------------------------------------------------------------
__global__ __launch_bounds__(256) void ln_bf16(const float* __restrict__ x,
    const float* __restrict__ w, const float* __restrict__ b, u16* __restrict__ out)
{
  const int row = blockIdx.x, tid = threadIdx.x;
  const float4 v = ((const float4*)(x + (size_t)row * 1024))[tid];
  float s = v.x + v.y + v.z + v.w;
  float s2 = v.x * v.x + v.y * v.y + v.z * v.z + v.w * v.w;
#pragma unroll
  for (int m = 32; m >= 1; m >>= 1) { s += __shfl_xor(s, m); s2 += __shfl_xor(s2, m); }
  __shared__ float red[8];
  if ((tid & 63) == 0) { red[tid >> 6] = s; red[4 + (tid >> 6)] = s2; }
  __syncthreads();
  s  = red[0] + red[1] + red[2] + red[3];
  s2 = red[4] + red[5] + red[6] + red[7];
  const float mu = s * (1.f / 1024.f);
  const float inv = rsqrtf(s2 * (1.f / 1024.f) - mu * mu + 1e-5f);
  const float4 wv = ((const float4*)w)[tid];
  const float4 bv = ((const float4*)b)[tid];
  ushort4 o;
  o.x = f2bf((v.x - mu) * inv * wv.x + bv.x);
  o.y = f2bf((v.y - mu) * inv * wv.y + bv.y);
  o.z = f2bf((v.z - mu) * inv * wv.z + bv.z);
  o.w = f2bf((v.w - mu) * inv * wv.w + bv.w);
  ((ushort4*)out)[(size_t)row * 256 + tid] = o;
}

// ---------------------------------------------------------------------------
// GEMM 128x128 v3 (counted-vmcnt pipeline, round-10 verified).
// EPI: 0 bf16 ; 3 bf16 with cols<1024 pre-scaled by SCL2.
// ---------------------------------------------------------------------------
#define BM 128
#define BN 128
#define BK 32

template<int EPI>
__global__ __launch_bounds__(256, 2) void gemm_bt(
    const u16* __restrict__ A, const u16* __restrict__ Bt, void* __restrict__ Cout,
    const float* __restrict__ bias, const float* __restrict__ resid,
    int M, int N, int K)
{
  __shared__ u16 As[4][BM * BK];
  __shared__ u16 Bs[4][BN * BK];
  const int tid = threadIdx.x;
  const int w = tid >> 6, lane = tid & 63;
  const int lo = lane & 15, hi = lane >> 4;
  const int mBase = blockIdx.x * BM, nBase = blockIdx.y * BN;
  const int wr = (w >> 1) * 64, wc = (w & 1) * 64;

  const f32x4 vzero = {0.f, 0.f, 0.f, 0.f};
  f32x4 acc[4][4];
#pragma unroll
  for (int i = 0; i < 4; ++i)
#pragma unroll
    for (int j = 0; j < 4; ++j) acc[i][j] = vzero;

  const int base0 = w * 2048 + lane * 16;
  int srow[2], skb[2];
#pragma unroll
  for (int c = 0; c < 2; ++c) {
    const int off = base0 + c * 1024;
    srow[c] = off >> 6;
    skb[c] = (off & 63) >> 1;
  }

  const int NT = K >> 5;

  auto stage = [&](int kt) {
    const int slot = kt & 3;
    const int k0 = kt * BK;
#pragma unroll
    for (int c = 0; c < 2; ++c) {
      const u16* ga = A  + (size_t)(mBase + srow[c]) * K + k0 + skb[c];
      const u16* gb = Bt + (size_t)(nBase + srow[c]) * K + k0 + skb[c];
      __builtin_amdgcn_global_load_lds((const __attribute__((address_space(1))) void*)ga,
          (__attribute__((address_space(3))) void*)((char*)&As[slot][0] + w * 2048 + c * 1024), 16, 0, 0);
      __builtin_amdgcn_global_load_lds((const __attribute__((address_space(1))) void*)gb,
          (__attribute__((address_space(3))) void*)((char*)&Bs[slot][0] + w * 2048 + c * 1024), 16, 0, 0);
    }
  };

  stage(0);
  stage(1);

  for (int kt = 0; kt < NT; ++kt) {
    if (kt + 2 < NT) {
      stage(kt + 2);
      asm volatile("s_waitcnt vmcnt(8)" ::: "memory");
    } else if (kt + 1 < NT) {
      asm volatile("s_waitcnt vmcnt(4)" ::: "memory");
    } else {
      asm volatile("s_waitcnt vmcnt(0)" ::: "memory");
    }
    __builtin_amdgcn_s_barrier();
    __builtin_amdgcn_sched_barrier(0);

    const int slot = kt & 3;
    short8 af[4], bf[4];
#pragma unroll
    for (int i = 0; i < 4; ++i) {
      af[i] = *(const short8*)((const char*)&As[slot][0] + (wr + i * 16 + lo) * 64 + hi * 16);
      bf[i] = *(const short8*)((const char*)&Bs[slot][0] + (wc + i * 16 + lo) * 64 + hi * 16);
    }
    __builtin_amdgcn_s_setprio(1);
#pragma unroll
    for (int i = 0; i < 4; ++i)
#pragma unroll
      for (int j = 0; j < 4; ++j)
        acc[i][j] = MFMA16(af[i], bf[j], acc[i][j]);
    __builtin_amdgcn_s_setprio(0);
  }

#pragma unroll
  for (int i = 0; i < 4; ++i) {
#pragma unroll
    for (int j = 0; j < 4; ++j) {
#pragma unroll
      for (int r = 0; r < 4; ++r) {
        const int row = mBase + wr + i * 16 + hi * 4 + r;
        const int col = nBase + wc + j * 16 + lo;
        float v = acc[i][j][r];
        if (EPI == 3 && col < 1024) v *= SCL2;
        ((u16*)Cout)[(size_t)row * N + col] = f2bf(v);
      }
    }
  }
}

// ---------------------------------------------------------------------------
// GEMM 128x64: 4-slot counted-vmcnt ring. Ks = row stride; K = loop extent
// per split; blockIdx.z selects the K-half (A/Bt advanced by z*K).
// EPI: 1 = +bias +resid -> fp32 ; 4 = bf16 partial (z=0 -> Cout, z=1 -> Cout2)
// ---------------------------------------------------------------------------
template<int EPI>
__global__ __launch_bounds__(256, 3) void gemm_n64(
    const u16* __restrict__ A, const u16* __restrict__ Bt,
    void* __restrict__ Cout, void* __restrict__ Cout2,
    const float* __restrict__ bias, const float* __restrict__ resid,
    int M, int N, int K, int Ks)
{
  __shared__ u16 As[4][128 * 32];   // 8 KB/slot
  __shared__ u16 Bs[4][64 * 32];    // 4 KB/slot
  const int tid = threadIdx.x;
  const int w = tid >> 6, lane = tid & 63;
  const int lo = lane & 15, hi = lane >> 4;
  const int mBase = blockIdx.x * 128, nBase = blockIdx.y * 64;
  const int wr = (w >> 1) * 64, wc = (w & 1) * 32;
  const int kOff = blockIdx.z * K;
  A += kOff; Bt += kOff;

  const f32x4 vzero = {0.f, 0.f, 0.f, 0.f};
  f32x4 acc[4][2];
#pragma unroll
  for (int i = 0; i < 4; ++i)
#pragma unroll
    for (int j = 0; j < 2; ++j) acc[i][j] = vzero;

  int arow[2], akb[2];
#pragma unroll
  for (int c = 0; c < 2; ++c) {
    const int off = tid * 16 + c * 4096;
    arow[c] = off >> 6;
    akb[c] = (off & 63) >> 1;
  }
  const int brow = (tid * 16) >> 6, bkb = ((tid * 16) & 63) >> 1;

  const int NT = K >> 5;

  auto stage = [&](int kt) {
    const int slot = kt & 3;
    const int k0 = kt * 32;
#pragma unroll
    for (int c = 0; c < 2; ++c) {
      const u16* ga = A + (size_t)(mBase + arow[c]) * Ks + k0 + akb[c];
      __builtin_amdgcn_global_load_lds((const __attribute__((address_space(1))) void*)ga,
          (__attribute__((address_space(3))) void*)((char*)&As[slot][0] + tid * 16 + c * 4096), 16, 0, 0);
    }
    const u16* gb = Bt + (size_t)(nBase + brow) * Ks + k0 + bkb;
    __builtin_amdgcn_global_load_lds((const __attribute__((address_space(1))) void*)gb,
        (__attribute__((address_space(3))) void*)((char*)&Bs[slot][0] + tid * 16), 16, 0, 0);
  };

  stage(0);
  stage(1);

  for (int kt = 0; kt < NT; ++kt) {
    if (kt + 2 < NT) {
      stage(kt + 2);
      asm volatile("s_waitcnt vmcnt(6)" ::: "memory");
    } else if (kt + 1 < NT) {
      asm volatile("s_waitcnt vmcnt(3)" ::: "memory");
    } else {
      asm volatile("s_waitcnt vmcnt(0)" ::: "memory");
    }
    __builtin_amdgcn_s_barrier();
    __builtin_amdgcn_sched_barrier(0);

    const int slot = kt & 3;
    short8 af[4], bf[2];
#pragma unroll
    for (int i = 0; i < 4; ++i)
      af[i] = *(const short8*)((const char*)&As[slot][0] + (wr + i * 16 + lo) * 64 + hi * 16);
#pragma unroll
    for (int j = 0; j < 2; ++j)
      bf[j] = *(const short8*)((const char*)&Bs[slot][0] + (wc + j * 16 + lo) * 64 + hi * 16);
    __builtin_amdgcn_s_setprio(1);
#pragma unroll
    for (int i = 0; i < 4; ++i)
#pragma unroll
      for (int j = 0; j < 2; ++j)
        acc[i][j] = MFMA16(af[i], bf[j], acc[i][j]);
    __builtin_amdgcn_s_setprio(0);
  }

  void* sel = (EPI == 4 && blockIdx.z) ? Cout2 : Cout;
#pragma unroll
  for (int i = 0; i < 4; ++i) {
#pragma unroll
    for (int j = 0; j < 2; ++j) {
#pragma unroll
      for (int r = 0; r < 4; ++r) {
        const int row = mBase + wr + i * 16 + hi * 4 + r;
        const int col = nBase + wc + j * 16 + lo;
        float v = acc[i][j][r];
        if (EPI == 1) {
          v += bias[col];
          v += resid[(size_t)row * N + col];
          ((float*)sel)[(size_t)row * N + col] = v;
        } else {
          ((u16*)sel)[(size_t)row * N + col] = f2bf(v);
        }
      }
    }
  }
}

// MLP2 split-K combine: out = p0 + p1 + bias + resid  (4096x1024 fp32)
__global__ __launch_bounds__(256) void mlp2_combine(const u16* __restrict__ p0,
    const u16* __restrict__ p1, const float* __restrict__ bias,
    const float* __restrict__ resid, float* __restrict__ out)
{
  const int tid = threadIdx.x;
  const int c0 = tid * 4;
  const float4 bv = *(const float4*)(bias + c0);
#pragma unroll
  for (int rr = 0; rr < 4; ++rr) {
    const int row = blockIdx.x * 4 + rr;
    const size_t off = (size_t)row * 1024 + c0;
    const ushort4 a = *(const ushort4*)(p0 + off);
    const ushort4 b = *(const ushort4*)(p1 + off);
    const float4 rv = *(const float4*)(resid + off);
    float4 o;
    o.x = bf2f(a.x) + bf2f(b.x) + bv.x + rv.x;
    o.y = bf2f(a.y) + bf2f(b.y) + bv.y + rv.y;
    o.z = bf2f(a.z) + bf2f(b.z) + bv.z + rv.z;
    o.w = bf2f(a.w) + bf2f(b.w) + bv.w + rv.w;
    *(float4*)(out + off) = o;
  }
}

// ---------------------------------------------------------------------------
// GEMM 256x256 v2 (flat schedule, round-9 verified) — unchanged
// ---------------------------------------------------------------------------
template<int EPI>
__global__ __launch_bounds__(512, 2) void gemm256(
    const u16* __restrict__ A, const u16* __restrict__ Bt, void* __restrict__ Cout,
    const float* __restrict__ bias, const float* __restrict__ resid,
    int M, int N, int K)
{
  __shared__ u16 lds8[2][2][2][8192];
  const int tid = threadIdx.x;
  const int lane = tid & 63, lo = lane & 15, hi = lane >> 4;
  const int wid = tid >> 6, wr = wid >> 2, wc = wid & 3;
  const int mBase = blockIdx.x * 256, nBase = blockIdx.y * 256;
  const int sw = (lo & 7) << 4;

  const f32x4 vzero = {0.f, 0.f, 0.f, 0.f};
  f32x4 acc[8][4];
#pragma unroll
  for (int i = 0; i < 8; ++i)
#pragma unroll
    for (int j = 0; j < 4; ++j) acc[i][j] = vzero;

  int srow[2], scol[2];
#pragma unroll
  for (int c = 0; c < 2; ++c) {
    const int p = c * 8192 + tid * 16;
    const int r = p >> 7, bb = p & 127;
    srow[c] = r;
    scol[c] = (bb ^ ((r & 7) << 4)) >> 1;
  }

  const int NT = K >> 6;

#pragma unroll
  for (int mat = 0; mat < 2; ++mat)
#pragma unroll
    for (int half = 0; half < 2; ++half)
#pragma unroll
      for (int c = 0; c < 2; ++c) {
        const u16* g = (mat == 0)
          ? A  + (size_t)(mBase + half * 128 + srow[c]) * K + scol[c]
          : Bt + (size_t)(nBase + half * 128 + srow[c]) * K + scol[c];
        __builtin_amdgcn_global_load_lds((const __attribute__((address_space(1))) void*)g,
            (__attribute__((address_space(3))) void*)(&lds8[0][mat][half][c * 4096 + tid * 8]), 16, 0, 0);
      }
  asm volatile("s_waitcnt vmcnt(0)" ::: "memory");
  asm volatile("s_barrier" ::: "memory");

  for (int kt = 0; kt < NT; ++kt) {
    const int cur = kt & 1;
    const char* baseA = (const char*)&lds8[cur][0][wr][0];
    const char* baseB = (const char*)&lds8[cur][1][wc >> 1][0];
    const int rBB = (wc & 1) * 64;

    short8 bfr[4][2], afr[4][2];
#pragma unroll
    for (int nf = 0; nf < 4; ++nf)
#pragma unroll
      for (int ks = 0; ks < 2; ++ks)
        bfr[nf][ks] = *(const short8*)(baseB + (rBB + nf * 16 + lo) * 128 + ((ks * 64 + hi * 16) ^ sw));
#pragma unroll
    for (int mf = 0; mf < 4; ++mf)
#pragma unroll
      for (int ks = 0; ks < 2; ++ks)
        afr[mf][ks] = *(const short8*)(baseA + ((mf * 16 + lo) * 128 + ((ks * 64 + hi * 16) ^ sw)));

    if (kt + 1 < NT) {
      const int ko = (kt + 1) * 64;
#pragma unroll
      for (int mat = 0; mat < 2; ++mat)
#pragma unroll
        for (int half = 0; half < 2; ++half)
#pragma unroll
          for (int c = 0; c < 2; ++c) {
            const u16* g = (mat == 0)
              ? A  + (size_t)(mBase + half * 128 + srow[c]) * K + ko + scol[c]
              : Bt + (size_t)(nBase + half * 128 + srow[c]) * K + ko + scol[c];
            __builtin_amdgcn_global_load_lds((const __attribute__((address_space(1))) void*)g,
                (__attribute__((address_space(3))) void*)(&lds8[cur ^ 1][mat][half][c * 4096 + tid * 8]), 16, 0, 0);
          }
    }

    __builtin_amdgcn_s_setprio(1);
#pragma unroll
    for (int mf = 0; mf < 4; ++mf)
#pragma unroll
      for (int nf = 0; nf < 4; ++nf)
#pragma unroll
        for (int ks = 0; ks < 2; ++ks)
          acc[mf][nf] = MFMA16(afr[mf][ks], bfr[nf][ks], acc[mf][nf]);
    __builtin_amdgcn_s_setprio(0);

#pragma unroll
    for (int mf = 0; mf < 4; ++mf)
#pragma unroll
      for (int ks = 0; ks < 2; ++ks)
        afr[mf][ks] = *(const short8*)(baseA + (((mf + 4) * 16 + lo) * 128 + ((ks * 64 + hi * 16) ^ sw)));

    __builtin_amdgcn_s_setprio(1);
#pragma unroll
    for (int mf = 0; mf < 4; ++mf)
#pragma unroll
      for (int nf = 0; nf < 4; ++nf)
#pragma unroll
        for (int ks = 0; ks < 2; ++ks)
          acc[mf + 4][nf] = MFMA16(afr[mf][ks], bfr[nf][ks], acc[mf + 4][nf]);
    __builtin_amdgcn_s_setprio(0);

    asm volatile("s_waitcnt vmcnt(0)" ::: "memory");
    asm volatile("s_barrier" ::: "memory");
  }

#pragma unroll
  for (int mf = 0; mf < 8; ++mf) {
#pragma unroll
    for (int nf = 0; nf < 4; ++nf) {
#pragma unroll
      for (int r = 0; r < 4; ++r) {
        const int row = mBase + wr * 128 + mf * 16 + hi * 4 + r;
        const int col = nBase + wc * 64 + nf * 16 + lo;
        float v = acc[mf][nf][r];
        if (EPI != 0) v += bias[col];
        if (EPI == 1) v += resid[(size_t)row * N + col];
        if (EPI == 2) v = 0.5f * v * (1.f + erff(v * 0.70710678118f));
        if (EPI == 1) ((float*)Cout)[(size_t)row * N + col] = v;
        else          ((u16*)Cout)[(size_t)row * N + col] = f2bf(v);
      }
    }
  }
}

// ---------------------------------------------------------------------------
// Flash attention v9 (round-14 verified): split-T + fixed-max softmax
// ---------------------------------------------------------------------------
__global__ __launch_bounds__(256) void attn_fwd(const u16* __restrict__ qkv,
    const u16* __restrict__ vt, u16* __restrict__ z,
    u16* __restrict__ zscr, float* __restrict__ lscr)
{
  __shared__ u16 Ks[2][64 * 64];
  __shared__ u16 Vs[2][64 * 64];
  __shared__ u16 Pl[4][32 * 72];
  const int tid = threadIdx.x;
  const int w = tid >> 6, lane = tid & 63, lo = lane & 15, hi = lane >> 4;
  const int bx = blockIdx.x;
  int chunk, itBeg, itEnd, mode;
  if (bx < 16)      { chunk = bx;      itBeg = 0;  itEnd = chunk + 1; mode = 0; }
  else if (bx < 32) { chunk = bx;      itBeg = 0;  itEnd = 16;        mode = 1; }
  else              { chunk = bx - 16; itBeg = 16; itEnd = chunk + 1; mode = 2; }
  const int bg = blockIdx.y, b = bg >> 3, g = bg & 7;
  const int h = (g << 1) | (w & 1);
  const int q0w = chunk * 64 + (w >> 1) * 32;
  const int sw = (lo & 7) << 4;

  short8 qA[2][2];
#pragma unroll
  for (int qf = 0; qf < 2; ++qf)
#pragma unroll
    for (int half = 0; half < 2; ++half)
      qA[qf][half] = *(const short8*)(qkv +
          (size_t)(b * 2048 + q0w + qf * 16 + lo) * 2048 + h * 64 + half * 32 + hi * 8);

  const f32x4 vzero = {0.f, 0.f, 0.f, 0.f};
  f32x4 zacc[2][4];
#pragma unroll
  for (int qf = 0; qf < 2; ++qf)
#pragma unroll
    for (int kf = 0; kf < 4; ++kf) zacc[qf][kf] = vzero;
  float lrun[2] = {0.f, 0.f};

  const u16* kbase = qkv + (size_t)b * 2048 * 2048 + 1024 + g * 64;
  const u16* vbase = vt + (size_t)(b * 8 + g) * 64 * 2048;

  int srow[2], scol[2];
#pragma unroll
  for (int c = 0; c < 2; ++c) {
    const int p = tid * 16 + c * 4096;
    const int r = p >> 7, bb = p & 127;
    srow[c] = r;
    scol[c] = (bb ^ ((r & 7) << 4)) >> 1;
  }

  u16* pw = &Pl[w][0];

  auto stageKV = [&](int it) {
    const int slot = it & 1;
    const int t0 = it * 64;
#pragma unroll
    for (int c = 0; c < 2; ++c) {
      __builtin_amdgcn_global_load_lds(
          (const __attribute__((address_space(1))) void*)(kbase + (size_t)(t0 + srow[c]) * 2048 + scol[c]),
          (__attribute__((address_space(3))) void*)((char*)&Ks[slot][0] + tid * 16 + c * 4096), 16, 0, 0);
      __builtin_amdgcn_global_load_lds(
          (const __attribute__((address_space(1))) void*)(vbase + (size_t)srow[c] * 2048 + t0 + scol[c]),
          (__attribute__((address_space(3))) void*)((char*)&Vs[slot][0] + tid * 16 + c * 4096), 16, 0, 0);
    }
  };

  stageKV(itBeg);

  for (int it = itBeg; it < itEnd; ++it) {
    asm volatile("s_waitcnt vmcnt(0)" ::: "memory");
    __builtin_amdgcn_s_barrier();
    __builtin_amdgcn_sched_barrier(0);
    if (it + 1 < itEnd) stageKV(it + 1);

    const int slot = it & 1;
    const int ts = it * 64;
    const char* KsB = (const char*)&Ks[slot][0];
    const char* VsB = (const char*)&Vs[slot][0];

    short8 kA[4][2];
#pragma unroll
    for (int nt = 0; nt < 4; ++nt)
#pragma unroll
      for (int half = 0; half < 2; ++half)
        kA[nt][half] = *(const short8*)(KsB + (nt * 16 + lo) * 128 + ((half * 64 + hi * 16) ^ sw));

#pragma unroll
    for (int qf = 0; qf < 2; ++qf) {
      f32x4 p[4];
#pragma unroll
      for (int nt = 0; nt < 4; ++nt) {
        f32x4 t = MFMA16(kA[nt][0], qA[qf][0], vzero);
        p[nt] = MFMA16(kA[nt][1], qA[qf][1], t);
      }
      const int qrow0 = q0w + qf * 16;
      if (ts + 63 > qrow0) {
        const int rel = qrow0 + lo - ts;
#pragma unroll
        for (int nt = 0; nt < 4; ++nt)
#pragma unroll
          for (int r = 0; r < 4; ++r)
            if (nt * 16 + hi * 4 + r > rel) p[nt][r] = -1e30f;
      }
#pragma unroll
      for (int nt = 0; nt < 4; ++nt)
#pragma unroll
        for (int r = 0; r < 4; ++r) p[nt][r] = exp2f(p[nt][r]);
      float s0 = (p[0][0] + p[0][1]) + (p[0][2] + p[0][3]);
      float s1 = (p[1][0] + p[1][1]) + (p[1][2] + p[1][3]);
      float s2 = (p[2][0] + p[2][1]) + (p[2][2] + p[2][3]);
      float s3 = (p[3][0] + p[3][1]) + (p[3][2] + p[3][3]);
      lrun[qf] += (s0 + s1) + (s2 + s3);
#pragma unroll
      for (int nt = 0; nt < 4; ++nt) {
        uint2 uu;
        uu.x = cvtpk(p[nt][0], p[nt][1]);
        uu.y = cvtpk(p[nt][2], p[nt][3]);
        *(uint2*)((char*)pw + (qf * 16 + lo) * 144 + nt * 32 + hi * 8) = uu;
      }
    }
    asm volatile("s_waitcnt lgkmcnt(0)" ::: "memory");
    short8 pa[2][2];
#pragma unroll
    for (int qf = 0; qf < 2; ++qf)
#pragma unroll
      for (int tc = 0; tc < 2; ++tc)
        pa[qf][tc] = *(const short8*)((const char*)pw + (qf * 16 + lo) * 144 + tc * 64 + hi * 16);
#pragma unroll
    for (int kf = 0; kf < 4; ++kf) {
#pragma unroll
      for (int tc = 0; tc < 2; ++tc) {
        const short8 vf = *(const short8*)(VsB + (kf * 16 + lo) * 128 + ((tc * 64 + hi * 16) ^ sw));
        zacc[0][kf] = MFMA16(vf, pa[0][tc], zacc[0][kf]);
        zacc[1][kf] = MFMA16(vf, pa[1][tc], zacc[1][kf]);
      }
    }
  }

  if (mode == 0) {
    u16* zp = z + (size_t)(b * 2048 + q0w) * 1024 + h * 64;
#pragma unroll
    for (int qf = 0; qf < 2; ++qf) {
      float rs = lrun[qf];
      rs += __shfl_xor(rs, 16);
      rs += __shfl_xor(rs, 32);
      const float inv = 1.f / rs;
#pragma unroll
      for (int kf = 0; kf < 4; ++kf) {
        uint2 o;
        o.x = cvtpk(zacc[qf][kf][0] * inv, zacc[qf][kf][1] * inv);
        o.y = cvtpk(zacc[qf][kf][2] * inv, zacc[qf][kf][3] * inv);
        *(uint2*)(zp + (size_t)(qf * 16 + lo) * 1024 + kf * 16 + hi * 4) = o;
      }
    }
  } else {
    const int seg = mode - 1;
    const int ci = chunk - 16;
    const int idx2 = (bg * 16 + ci) * 2 + (w & 1);
    u16* zs = zscr + ((size_t)seg * 512 * 4096) + ((size_t)idx2 * 64 + (w >> 1) * 32) * 64;
    float* ls = lscr + (size_t)seg * 512 * 64 + (size_t)idx2 * 64 + (w >> 1) * 32;
#pragma unroll
    for (int qf = 0; qf < 2; ++qf) {
      float rs = lrun[qf];
      rs += __shfl_xor(rs, 16);
      rs += __shfl_xor(rs, 32);
      if (hi == 0) ls[qf * 16 + lo] = rs;
#pragma unroll
      for (int kf = 0; kf < 4; ++kf) {
        uint2 o;
        o.x = cvtpk(zacc[qf][kf][0], zacc[qf][kf][1]);
        o.y = cvtpk(zacc[qf][kf][2], zacc[qf][kf][3]);
        *(uint2*)(zs + (size_t)(qf * 16 + lo) * 64 + kf * 16 + hi * 4) = o;
      }
    }
  }
}

// Combine: z[rows of chunks 16..31] = (z0+z1) / (l0+l1)
__global__ __launch_bounds__(256) void attn_combine(const u16* __restrict__ zscr,
    const float* __restrict__ lscr, u16* __restrict__ z)
{
  const int bgci = blockIdx.x;
  const int bg = bgci >> 4, ci = bgci & 15;
  const int b = bg >> 3, g = bg & 7, chunk = 16 + ci;
  const int tid = threadIdx.x;
#pragma unroll
  for (int j = 0; j < 4; ++j) {
    const int v = tid + j * 256;
    const int k8 = v & 7, row = (v >> 3) & 63, hh = v >> 9;
    const size_t base = ((size_t)(bgci * 2 + hh) * 64 + row) * 64 + k8 * 8;
    const short8 z0 = *(const short8*)(zscr + base);
    const short8 z1 = *(const short8*)(zscr + (size_t)512 * 4096 + base);
    const size_t lidx = (size_t)(bgci * 2 + hh) * 64 + row;
    const float inv = 1.f / (lscr[lidx] + lscr[(size_t)512 * 64 + lidx]);
    float a[8];
#pragma unroll
    for (int e = 0; e < 8; ++e)
      a[e] = (bf2f((u16)z0[e]) + bf2f((u16)z1[e])) * inv;
    uint4 o;
    o.x = cvtpk(a[0], a[1]);
    o.y = cvtpk(a[2], a[3]);
    o.z = cvtpk(a[4], a[5]);
    o.w = cvtpk(a[6], a[7]);
    *(uint4*)(z + ((size_t)(b * 2048 + chunk * 64 + row)) * 1024 + (g * 2 + hh) * 64 + k8 * 8) = o;
  }
}

// ---------------------------------------------------------------------------

extern "C" void kernel_launch(void* const* d_in, const int* in_sizes, int n_in,
                              void* d_out, int out_size, void* d_ws, size_t ws_size,
                              hipStream_t stream)
{
  (void)in_sizes; (void)n_in; (void)out_size; (void)ws_size;
  const float* x      = (const float*)d_in[0];
  const float* ln1_w  = (const float*)d_in[1];
  const float* ln1_b  = (const float*)d_in[2];
  const float* W_Q    = (const float*)d_in[3];
  const float* W_K    = (const float*)d_in[4];
  const float* W_V    = (const float*)d_in[5];
  const float* W_out  = (const float*)d_in[6];
  const float* b_out  = (const float*)d_in[7];
  const float* ln2_w  = (const float*)d_in[8];
  const float* ln2_b  = (const float*)d_in[9];
  const float* mlp1_w = (const float*)d_in[10];
  const float* mlp1_b = (const float*)d_in[11];
  const float* mlp2_w = (const float*)d_in[12];
  const float* mlp2_b = (const float*)d_in[13];
  float* out = (float*)d_out;

  char* ws = (char*)d_ws;
  u16*   wqkv_t = (u16*)(ws + 0);           // [2048][1024] bf16   4 MB
  u16*   wout_t = (u16*)(ws + 4194304);     // [1024][1024] bf16   2 MB
  u16*   w1     = (u16*)(ws + 6291456);     // [4096][1024] bf16   8 MB
  u16*   w2     = (u16*)(ws + 14680064);    // [1024][4096] bf16   8 MB
  u16*   normed = (u16*)(ws + 23068672);    // [4096][1024] bf16   8 MB (lscr; mlp2 p1)
  float* post   = (float*)(ws + 31457280);  // [4096][1024] f32   16 MB (zscr during attn)
  u16*   qkv    = (u16*)(ws + 48234496);    // [4096][2048] bf16  16 MB
  u16*   vtb    = (u16*)(ws + 65011712);    // [16][64][2048] bf16 4 MB
  u16*   zb     = (u16*)(ws + 69206016);    // [4096][1024] bf16   8 MB
  u16*   hbuf   = (u16*)(ws + 48234496);    // [4096][4096] bf16  32 MB (reuses qkv/vt/z)
  u16*   zscr   = (u16*)(ws + 31457280);    // 8.4 MB partial z (inside post region)
  float* lscr   = (float*)(ws + 23068672);  // 262 KB partial l (inside normed region)
  u16*   mp0    = (u16*)(ws + 0);           // MLP2 K-half-0 partial, 8 MB (wqkv_t/wout_t dead)
  u16*   mp1    = (u16*)(ws + 23068672);    // MLP2 K-half-1 partial, 8 MB (normed dead)

  prep_wqkv<<<dim3(64, 32), 256, 0, stream>>>(W_Q, W_K, W_V, wqkv_t);
  prep_wout<<<dim3(32, 32), 256, 0, stream>>>(W_out, wout_t);
  convert_bf16<<<4096, 256, 0, stream>>>((const float4*)mlp1_w, w1, 1048576);
  convert_bf16<<<4096, 256, 0, stream>>>((const float4*)mlp2_w, w2, 1048576);

  ln_bf16<<<4096, 256, 0, stream>>>(x, ln1_w, ln1_b, normed);
  gemm_bt<3><<<dim3(32, 16), 256, 0, stream>>>(normed, wqkv_t, qkv, nullptr, nullptr, 4096, 2048, 1024);
  vt_transpose<<<dim3(64, 2, 16), 256, 0, stream>>>(qkv, vtb);
  attn_fwd<<<dim3(48, 16), 256, 0, stream>>>(qkv, vtb, zb, zscr, lscr);
  attn_combine<<<256, 256, 0, stream>>>(zscr, lscr, zb);
  gemm_n64<1><<<dim3(32, 16), 256, 0, stream>>>(zb, wout_t, post, nullptr, b_out, x, 4096, 1024, 1024, 1024);
  ln_bf16<<<4096, 256, 0, stream>>>(post, ln2_w, ln2_b, normed);
  gemm256<2><<<dim3(16, 16), 512, 0, stream>>>(normed, w1, hbuf, mlp1_b, nullptr, 4096, 4096, 1024);
  gemm_n64<4><<<dim3(32, 16, 2), 256, 0, stream>>>(hbuf, w2, mp0, mp1, nullptr, nullptr, 4096, 1024, 2048, 4096);
  mlp2_combine<<<1024, 256, 0, stream>>>(mp0, mp1, mlp2_b, post, out);
}

// Round 17
// 248.703 us; speedup vs baseline: 1.0454x; 1.0454x over previous
//
#include <hip/hip_runtime.h>
#include <cstdint>
#include <cstddef>

typedef __attribute__((ext_vector_type(8))) short short8;
typedef __attribute__((ext_vector_type(4))) float f32x4;
typedef unsigned short u16;

#define MFMA16(a, b, c) __builtin_amdgcn_mfma_f32_16x16x32_bf16((a), (b), (c), 0, 0, 0)
#define SCL2 0.18033688011112042f   /* 0.125 * log2(e) */

__device__ __forceinline__ u16 f2bf(float f) {
  union { float f; unsigned u; } c; c.f = f;
  unsigned r = c.u + 0x7fffu + ((c.u >> 16) & 1u);
  return (u16)(r >> 16);
}

__device__ __forceinline__ float bf2f(u16 x) {
  union { unsigned u; float f; } c; c.u = ((unsigned)x) << 16;
  return c.f;
}

__device__ __forceinline__ unsigned cvtpk(float a, float b) {
  unsigned r;
  asm("v_cvt_pk_bf16_f32 %0, %1, %2" : "=v"(r) : "v"(a), "v"(b));
  return r;
}

// ---------------------------------------------------------------------------
// Weight prep kernels (run every call; stateless)
// ---------------------------------------------------------------------------

__global__ __launch_bounds__(256) void prep_wqkv(const float* __restrict__ wq,
    const float* __restrict__ wk, const float* __restrict__ wv, u16* __restrict__ outp)
{
  __shared__ float t[32][33];
  const int tx = threadIdx.x & 31, ty = threadIdx.x >> 5;
  const int n0 = blockIdx.x * 32, d0 = blockIdx.y * 32;
  const float* src; int stride, nc;
  if (n0 < 1024)      { src = wq; stride = 1024; nc = n0; }
  else if (n0 < 1536) { src = wk; stride = 512;  nc = n0 - 1024; }
  else                { src = wv; stride = 512;  nc = n0 - 1536; }
#pragma unroll
  for (int i = 0; i < 32; i += 8)
    t[ty + i][tx] = src[(size_t)(d0 + ty + i) * stride + nc + tx];
  __syncthreads();
#pragma unroll
  for (int i = 0; i < 32; i += 8)
    outp[(size_t)(n0 + ty + i) * 1024 + d0 + tx] = f2bf(t[tx][ty + i]);
}

__global__ __launch_bounds__(256) void prep_wout(const float* __restrict__ wo, u16* __restrict__ outp)
{
  __shared__ float t[32][33];
  const int tx = threadIdx.x & 31, ty = threadIdx.x >> 5;
  const int d0 = blockIdx.x * 32, c0 = blockIdx.y * 32;
#pragma unroll
  for (int i = 0; i < 32; i += 8) {
    int c = c0 + ty + i;
    t[ty + i][tx] = wo[(size_t)(c & 63) * 16384 + (size_t)(c >> 6) * 1024 + d0 + tx];
  }
  __syncthreads();
#pragma unroll
  for (int i = 0; i < 32; i += 8)
    outp[(size_t)(d0 + ty + i) * 1024 + c0 + tx] = f2bf(t[tx][ty + i]);
}

__global__ void convert_bf16(const float4* __restrict__ in, u16* __restrict__ out, int n4) {
  int i = blockIdx.x * 256 + threadIdx.x;
  if (i >= n4) return;
  float4 v = in[i];
  ushort4 o; o.x = f2bf(v.x); o.y = f2bf(v.y); o.z = f2bf(v.z); o.w = f2bf(v.w);
  ((ushort4*)out)[i] = o;
}

// Vt[b][g][k][t] from qkv cols 1536+g*64+k
__global__ __launch_bounds__(256) void vt_transpose(const u16* __restrict__ qkv, u16* __restrict__ vtp)
{
  __shared__ u16 t[32][33];
  const int tx = threadIdx.x & 31, ty = threadIdx.x >> 5;
  const int t0 = blockIdx.x * 32, k0 = blockIdx.y * 32;
  const int bg = blockIdx.z, b = bg >> 3, g = bg & 7;
#pragma unroll
  for (int i = 0; i < 32; i += 8)
    t[ty + i][tx] = qkv[(size_t)(b * 2048 + t0 + ty + i) * 2048 + 1536 + g * 64 + k0 + tx];
  __syncthreads();
#pragma unroll
  for (int i = 0; i < 32; i += 8)
    vtp[(size_t)(bg * 64 + k0 + ty + i) * 2048 + t0 + tx] = t[tx][ty + i];
}

// ---------------------------------------------------------------------------
// LayerNorm (fp32 in -> bf16 out)
// ---------------------------------------------------------------------------
__global__ __launch_bounds__(256) void ln_bf16(const float* __restrict__ x,
    const float* __restrict__ w, const float* __restrict__ b, u16* __restrict__ out)
{
  const int row = blockIdx.x, tid = threadIdx.x;
  const float4 v = ((const float4*)(x + (size_t)row * 1024))[tid];
  float s = v.x + v.y + v.z + v.w;
  float s2 = v.x * v.x + v.y * v.y + v.z * v.z + v.w * v.w;
#pragma unroll
  for (int m = 32; m >= 1; m >>= 1) { s += __shfl_xor(s, m); s2 += __shfl_xor(s2, m); }
  __shared__ float red[8];
  if ((tid & 63) == 0) { red[tid >> 6] = s; red[4 + (tid >> 6)] = s2; }
  __syncthreads();
  s  = red[0] + red[1] + red[2] + red[3];
  s2 = red[4] + red[5] + red[6] + red[7];
  const float mu = s * (1.f / 1024.f);
  const float inv = rsqrtf(s2 * (1.f / 1024.f) - mu * mu + 1e-5f);
  const float4 wv = ((const float4*)w)[tid];
  const float4 bv = ((const float4*)b)[tid];
  ushort4 o;
  o.x = f2bf((v.x - mu) * inv * wv.x + bv.x);
  o.y = f2bf((v.y - mu) * inv * wv.y + bv.y);
  o.z = f2bf((v.z - mu) * inv * wv.z + bv.z);
  o.w = f2bf((v.w - mu) * inv * wv.w + bv.w);
  ((ushort4*)out)[(size_t)row * 256 + tid] = o;
}

// ---------------------------------------------------------------------------
// GEMM 128x128 v4: counted-vmcnt pipeline + T2 swizzle (64B-row variant,
// byte ^= (row&3)<<4; linear LDS dest, inverse-swizzled global src,
// swizzled ds_read). EPI: 0 bf16 ; 3 bf16 with cols<1024 pre-scaled.
// ---------------------------------------------------------------------------
#define BM 128
#define BN 128
#define BK 32

template<int EPI>
__global__ __launch_bounds__(256, 2) void gemm_bt(
    const u16* __restrict__ A, const u16* __restrict__ Bt, void* __restrict__ Cout,
    const float* __restrict__ bias, const float* __restrict__ resid,
    int M, int N, int K)
{
  __shared__ u16 As[4][BM * BK];
  __shared__ u16 Bs[4][BN * BK];
  const int tid = threadIdx.x;
  const int w = tid >> 6, lane = tid & 63;
  const int lo = lane & 15, hi = lane >> 4;
  const int mBase = blockIdx.x * BM, nBase = blockIdx.y * BN;
  const int wr = (w >> 1) * 64, wc = (w & 1) * 64;

  const f32x4 vzero = {0.f, 0.f, 0.f, 0.f};
  f32x4 acc[4][4];
#pragma unroll
  for (int i = 0; i < 4; ++i)
#pragma unroll
    for (int j = 0; j < 4; ++j) acc[i][j] = vzero;

  const int base0 = w * 2048 + lane * 16;
  int srow[2], skb[2];
#pragma unroll
  for (int c = 0; c < 2; ++c) {
    const int off = base0 + c * 1024;
    srow[c] = off >> 6;
    skb[c] = ((off & 63) ^ ((srow[c] & 3) << 4)) >> 1;   // inverse-swizzled k-offset
  }

  const int NT = K >> 5;

  auto stage = [&](int kt) {
    const int slot = kt & 3;
    const int k0 = kt * BK;
#pragma unroll
    for (int c = 0; c < 2; ++c) {
      const u16* ga = A  + (size_t)(mBase + srow[c]) * K + k0 + skb[c];
      const u16* gb = Bt + (size_t)(nBase + srow[c]) * K + k0 + skb[c];
      __builtin_amdgcn_global_load_lds((const __attribute__((address_space(1))) void*)ga,
          (__attribute__((address_space(3))) void*)((char*)&As[slot][0] + w * 2048 + c * 1024), 16, 0, 0);
      __builtin_amdgcn_global_load_lds((const __attribute__((address_space(1))) void*)gb,
          (__attribute__((address_space(3))) void*)((char*)&Bs[slot][0] + w * 2048 + c * 1024), 16, 0, 0);
    }
  };

  stage(0);
  stage(1);

  for (int kt = 0; kt < NT; ++kt) {
    if (kt + 2 < NT) {
      stage(kt + 2);
      asm volatile("s_waitcnt vmcnt(8)" ::: "memory");
    } else if (kt + 1 < NT) {
      asm volatile("s_waitcnt vmcnt(4)" ::: "memory");
    } else {
      asm volatile("s_waitcnt vmcnt(0)" ::: "memory");
    }
    __builtin_amdgcn_s_barrier();
    __builtin_amdgcn_sched_barrier(0);

    const int slot = kt & 3;
    short8 af[4], bf[4];
#pragma unroll
    for (int i = 0; i < 4; ++i) {
      const int ra = wr + i * 16 + lo;
      const int rb = wc + i * 16 + lo;
      af[i] = *(const short8*)((const char*)&As[slot][0] + ra * 64 + ((hi * 16) ^ ((ra & 3) << 4)));
      bf[i] = *(const short8*)((const char*)&Bs[slot][0] + rb * 64 + ((hi * 16) ^ ((rb & 3) << 4)));
    }
    __builtin_amdgcn_s_setprio(1);
#pragma unroll
    for (int i = 0; i < 4; ++i)
#pragma unroll
      for (int j = 0; j < 4; ++j)
        acc[i][j] = MFMA16(af[i], bf[j], acc[i][j]);
    __builtin_amdgcn_s_setprio(0);
  }

#pragma unroll
  for (int i = 0; i < 4; ++i) {
#pragma unroll
    for (int j = 0; j < 4; ++j) {
#pragma unroll
      for (int r = 0; r < 4; ++r) {
        const int row = mBase + wr + i * 16 + hi * 4 + r;
        const int col = nBase + wc + j * 16 + lo;
        float v = acc[i][j][r];
        if (EPI == 3 && col < 1024) v *= SCL2;
        ((u16*)Cout)[(size_t)row * N + col] = f2bf(v);
      }
    }
  }
}

// ---------------------------------------------------------------------------
// GEMM 128x64 v2 (N=1024 GEMMs): counted-vmcnt ring + T2 swizzle (64B rows).
// EPI 1 = +bias +resid -> fp32.
// ---------------------------------------------------------------------------
template<int EPI>
__global__ __launch_bounds__(256, 3) void gemm_n64(
    const u16* __restrict__ A, const u16* __restrict__ Bt, void* __restrict__ Cout,
    const float* __restrict__ bias, const float* __restrict__ resid,
    int M, int N, int K)
{
  __shared__ u16 As[4][128 * 32];   // 8 KB/slot
  __shared__ u16 Bs[4][64 * 32];    // 4 KB/slot
  const int tid = threadIdx.x;
  const int w = tid >> 6, lane = tid & 63;
  const int lo = lane & 15, hi = lane >> 4;
  const int mBase = blockIdx.x * 128, nBase = blockIdx.y * 64;
  const int wr = (w >> 1) * 64, wc = (w & 1) * 32;

  const f32x4 vzero = {0.f, 0.f, 0.f, 0.f};
  f32x4 acc[4][2];
#pragma unroll
  for (int i = 0; i < 4; ++i)
#pragma unroll
    for (int j = 0; j < 2; ++j) acc[i][j] = vzero;

  int arow[2], akb[2];
#pragma unroll
  for (int c = 0; c < 2; ++c) {
    const int off = tid * 16 + c * 4096;
    arow[c] = off >> 6;
    akb[c] = ((off & 63) ^ ((arow[c] & 3) << 4)) >> 1;
  }
  const int boff = tid * 16;
  const int brow = boff >> 6;
  const int bkb = ((boff & 63) ^ ((brow & 3) << 4)) >> 1;

  const int NT = K >> 5;

  auto stage = [&](int kt) {
    const int slot = kt & 3;
    const int k0 = kt * 32;
#pragma unroll
    for (int c = 0; c < 2; ++c) {
      const u16* ga = A + (size_t)(mBase + arow[c]) * K + k0 + akb[c];
      __builtin_amdgcn_global_load_lds((const __attribute__((address_space(1))) void*)ga,
          (__attribute__((address_space(3))) void*)((char*)&As[slot][0] + tid * 16 + c * 4096), 16, 0, 0);
    }
    const u16* gb = Bt + (size_t)(nBase + brow) * K + k0 + bkb;
    __builtin_amdgcn_global_load_lds((const __attribute__((address_space(1))) void*)gb,
        (__attribute__((address_space(3))) void*)((char*)&Bs[slot][0] + tid * 16), 16, 0, 0);
  };

  stage(0);
  stage(1);

  for (int kt = 0; kt < NT; ++kt) {
    if (kt + 2 < NT) {
      stage(kt + 2);
      asm volatile("s_waitcnt vmcnt(6)" ::: "memory");
    } else if (kt + 1 < NT) {
      asm volatile("s_waitcnt vmcnt(3)" ::: "memory");
    } else {
      asm volatile("s_waitcnt vmcnt(0)" ::: "memory");
    }
    __builtin_amdgcn_s_barrier();
    __builtin_amdgcn_sched_barrier(0);

    const int slot = kt & 3;
    short8 af[4], bf[2];
#pragma unroll
    for (int i = 0; i < 4; ++i) {
      const int ra = wr + i * 16 + lo;
      af[i] = *(const short8*)((const char*)&As[slot][0] + ra * 64 + ((hi * 16) ^ ((ra & 3) << 4)));
    }
#pragma unroll
    for (int j = 0; j < 2; ++j) {
      const int rb = wc + j * 16 + lo;
      bf[j] = *(const short8*)((const char*)&Bs[slot][0] + rb * 64 + ((hi * 16) ^ ((rb & 3) << 4)));
    }
    __builtin_amdgcn_s_setprio(1);
#pragma unroll
    for (int i = 0; i < 4; ++i)
#pragma unroll
      for (int j = 0; j < 2; ++j)
        acc[i][j] = MFMA16(af[i], bf[j], acc[i][j]);
    __builtin_amdgcn_s_setprio(0);
  }

#pragma unroll
  for (int i = 0; i < 4; ++i) {
#pragma unroll
    for (int j = 0; j < 2; ++j) {
#pragma unroll
      for (int r = 0; r < 4; ++r) {
        const int row = mBase + wr + i * 16 + hi * 4 + r;
        const int col = nBase + wc + j * 16 + lo;
        float v = acc[i][j][r];
        v += bias[col];
        v += resid[(size_t)row * N + col];
        ((float*)Cout)[(size_t)row * N + col] = v;
      }
    }
  }
}

// ---------------------------------------------------------------------------
// GEMM 256x256 v2 (flat schedule, round-9 verified) — unchanged
// ---------------------------------------------------------------------------
template<int EPI>
__global__ __launch_bounds__(512, 2) void gemm256(
    const u16* __restrict__ A, const u16* __restrict__ Bt, void* __restrict__ Cout,
    const float* __restrict__ bias, const float* __restrict__ resid,
    int M, int N, int K)
{
  __shared__ u16 lds8[2][2][2][8192];
  const int tid = threadIdx.x;
  const int lane = tid & 63, lo = lane & 15, hi = lane >> 4;
  const int wid = tid >> 6, wr = wid >> 2, wc = wid & 3;
  const int mBase = blockIdx.x * 256, nBase = blockIdx.y * 256;
  const int sw = (lo & 7) << 4;

  const f32x4 vzero = {0.f, 0.f, 0.f, 0.f};
  f32x4 acc[8][4];
#pragma unroll
  for (int i = 0; i < 8; ++i)
#pragma unroll
    for (int j = 0; j < 4; ++j) acc[i][j] = vzero;

  int srow[2], scol[2];
#pragma unroll
  for (int c = 0; c < 2; ++c) {
    const int p = c * 8192 + tid * 16;
    const int r = p >> 7, bb = p & 127;
    srow[c] = r;
    scol[c] = (bb ^ ((r & 7) << 4)) >> 1;
  }

  const int NT = K >> 6;

#pragma unroll
  for (int mat = 0; mat < 2; ++mat)
#pragma unroll
    for (int half = 0; half < 2; ++half)
#pragma unroll
      for (int c = 0; c < 2; ++c) {
        const u16* g = (mat == 0)
          ? A  + (size_t)(mBase + half * 128 + srow[c]) * K + scol[c]
          : Bt + (size_t)(nBase + half * 128 + srow[c]) * K + scol[c];
        __builtin_amdgcn_global_load_lds((const __attribute__((address_space(1))) void*)g,
            (__attribute__((address_space(3))) void*)(&lds8[0][mat][half][c * 4096 + tid * 8]), 16, 0, 0);
      }
  asm volatile("s_waitcnt vmcnt(0)" ::: "memory");
  asm volatile("s_barrier" ::: "memory");

  for (int kt = 0; kt < NT; ++kt) {
    const int cur = kt & 1;
    const char* baseA = (const char*)&lds8[cur][0][wr][0];
    const char* baseB = (const char*)&lds8[cur][1][wc >> 1][0];
    const int rBB = (wc & 1) * 64;

    short8 bfr[4][2], afr[4][2];
#pragma unroll
    for (int nf = 0; nf < 4; ++nf)
#pragma unroll
      for (int ks = 0; ks < 2; ++ks)
        bfr[nf][ks] = *(const short8*)(baseB + (rBB + nf * 16 + lo) * 128 + ((ks * 64 + hi * 16) ^ sw));
#pragma unroll
    for (int mf = 0; mf < 4; ++mf)
#pragma unroll
      for (int ks = 0; ks < 2; ++ks)
        afr[mf][ks] = *(const short8*)(baseA + ((mf * 16 + lo) * 128 + ((ks * 64 + hi * 16) ^ sw)));

    if (kt + 1 < NT) {
      const int ko = (kt + 1) * 64;
#pragma unroll
      for (int mat = 0; mat < 2; ++mat)
#pragma unroll
        for (int half = 0; half < 2; ++half)
#pragma unroll
          for (int c = 0; c < 2; ++c) {
            const u16* g = (mat == 0)
              ? A  + (size_t)(mBase + half * 128 + srow[c]) * K + ko + scol[c]
              : Bt + (size_t)(nBase + half * 128 + srow[c]) * K + ko + scol[c];
            __builtin_amdgcn_global_load_lds((const __attribute__((address_space(1))) void*)g,
                (__attribute__((address_space(3))) void*)(&lds8[cur ^ 1][mat][half][c * 4096 + tid * 8]), 16, 0, 0);
          }
    }

    __builtin_amdgcn_s_setprio(1);
#pragma unroll
    for (int mf = 0; mf < 4; ++mf)
#pragma unroll
      for (int nf = 0; nf < 4; ++nf)
#pragma unroll
        for (int ks = 0; ks < 2; ++ks)
          acc[mf][nf] = MFMA16(afr[mf][ks], bfr[nf][ks], acc[mf][nf]);
    __builtin_amdgcn_s_setprio(0);

#pragma unroll
    for (int mf = 0; mf < 4; ++mf)
#pragma unroll
      for (int ks = 0; ks < 2; ++ks)
        afr[mf][ks] = *(const short8*)(baseA + (((mf + 4) * 16 + lo) * 128 + ((ks * 64 + hi * 16) ^ sw)));

    __builtin_amdgcn_s_setprio(1);
#pragma unroll
    for (int mf = 0; mf < 4; ++mf)
#pragma unroll
      for (int nf = 0; nf < 4; ++nf)
#pragma unroll
        for (int ks = 0; ks < 2; ++ks)
          acc[mf + 4][nf] = MFMA16(afr[mf][ks], bfr[nf][ks], acc[mf + 4][nf]);
    __builtin_amdgcn_s_setprio(0);

    asm volatile("s_waitcnt vmcnt(0)" ::: "memory");
    asm volatile("s_barrier" ::: "memory");
  }

#pragma unroll
  for (int mf = 0; mf < 8; ++mf) {
#pragma unroll
    for (int nf = 0; nf < 4; ++nf) {
#pragma unroll
      for (int r = 0; r < 4; ++r) {
        const int row = mBase + wr * 128 + mf * 16 + hi * 4 + r;
        const int col = nBase + wc * 64 + nf * 16 + lo;
        float v = acc[mf][nf][r];
        if (EPI != 0) v += bias[col];
        if (EPI == 1) v += resid[(size_t)row * N + col];
        if (EPI == 2) v = 0.5f * v * (1.f + erff(v * 0.70710678118f));
        if (EPI == 1) ((float*)Cout)[(size_t)row * N + col] = v;
        else          ((u16*)Cout)[(size_t)row * N + col] = f2bf(v);
      }
    }
  }
}

// ---------------------------------------------------------------------------
// Flash attention v9 (round-14 verified): split-T + fixed-max softmax
// ---------------------------------------------------------------------------
__global__ __launch_bounds__(256) void attn_fwd(const u16* __restrict__ qkv,
    const u16* __restrict__ vt, u16* __restrict__ z,
    u16* __restrict__ zscr, float* __restrict__ lscr)
{
  __shared__ u16 Ks[2][64 * 64];
  __shared__ u16 Vs[2][64 * 64];
  __shared__ u16 Pl[4][32 * 72];
  const int tid = threadIdx.x;
  const int w = tid >> 6, lane = tid & 63, lo = lane & 15, hi = lane >> 4;
  const int bx = blockIdx.x;
  int chunk, itBeg, itEnd, mode;
  if (bx < 16)      { chunk = bx;      itBeg = 0;  itEnd = chunk + 1; mode = 0; }
  else if (bx < 32) { chunk = bx;      itBeg = 0;  itEnd = 16;        mode = 1; }
  else              { chunk = bx - 16; itBeg = 16; itEnd = chunk + 1; mode = 2; }
  const int bg = blockIdx.y, b = bg >> 3, g = bg & 7;
  const int h = (g << 1) | (w & 1);
  const int q0w = chunk * 64 + (w >> 1) * 32;
  const int sw = (lo & 7) << 4;

  short8 qA[2][2];
#pragma unroll
  for (int qf = 0; qf < 2; ++qf)
#pragma unroll
    for (int half = 0; half < 2; ++half)
      qA[qf][half] = *(const short8*)(qkv +
          (size_t)(b * 2048 + q0w + qf * 16 + lo) * 2048 + h * 64 + half * 32 + hi * 8);

  const f32x4 vzero = {0.f, 0.f, 0.f, 0.f};
  f32x4 zacc[2][4];
#pragma unroll
  for (int qf = 0; qf < 2; ++qf)
#pragma unroll
    for (int kf = 0; kf < 4; ++kf) zacc[qf][kf] = vzero;
  float lrun[2] = {0.f, 0.f};

  const u16* kbase = qkv + (size_t)b * 2048 * 2048 + 1024 + g * 64;
  const u16* vbase = vt + (size_t)(b * 8 + g) * 64 * 2048;

  int srow[2], scol[2];
#pragma unroll
  for (int c = 0; c < 2; ++c) {
    const int p = tid * 16 + c * 4096;
    const int r = p >> 7, bb = p & 127;
    srow[c] = r;
    scol[c] = (bb ^ ((r & 7) << 4)) >> 1;
  }

  u16* pw = &Pl[w][0];

  auto stageKV = [&](int it) {
    const int slot = it & 1;
    const int t0 = it * 64;
#pragma unroll
    for (int c = 0; c < 2; ++c) {
      __builtin_amdgcn_global_load_lds(
          (const __attribute__((address_space(1))) void*)(kbase + (size_t)(t0 + srow[c]) * 2048 + scol[c]),
          (__attribute__((address_space(3))) void*)((char*)&Ks[slot][0] + tid * 16 + c * 4096), 16, 0, 0);
      __builtin_amdgcn_global_load_lds(
          (const __attribute__((address_space(1))) void*)(vbase + (size_t)srow[c] * 2048 + t0 + scol[c]),
          (__attribute__((address_space(3))) void*)((char*)&Vs[slot][0] + tid * 16 + c * 4096), 16, 0, 0);
    }
  };

  stageKV(itBeg);

  for (int it = itBeg; it < itEnd; ++it) {
    asm volatile("s_waitcnt vmcnt(0)" ::: "memory");
    __builtin_amdgcn_s_barrier();
    __builtin_amdgcn_sched_barrier(0);
    if (it + 1 < itEnd) stageKV(it + 1);

    const int slot = it & 1;
    const int ts = it * 64;
    const char* KsB = (const char*)&Ks[slot][0];
    const char* VsB = (const char*)&Vs[slot][0];

    short8 kA[4][2];
#pragma unroll
    for (int nt = 0; nt < 4; ++nt)
#pragma unroll
      for (int half = 0; half < 2; ++half)
        kA[nt][half] = *(const short8*)(KsB + (nt * 16 + lo) * 128 + ((half * 64 + hi * 16) ^ sw));

#pragma unroll
    for (int qf = 0; qf < 2; ++qf) {
      f32x4 p[4];
#pragma unroll
      for (int nt = 0; nt < 4; ++nt) {
        f32x4 t = MFMA16(kA[nt][0], qA[qf][0], vzero);
        p[nt] = MFMA16(kA[nt][1], qA[qf][1], t);
      }
      const int qrow0 = q0w + qf * 16;
      if (ts + 63 > qrow0) {
        const int rel = qrow0 + lo - ts;
#pragma unroll
        for (int nt = 0; nt < 4; ++nt)
#pragma unroll
          for (int r = 0; r < 4; ++r)
            if (nt * 16 + hi * 4 + r > rel) p[nt][r] = -1e30f;
      }
#pragma unroll
      for (int nt = 0; nt < 4; ++nt)
#pragma unroll
        for (int r = 0; r < 4; ++r) p[nt][r] = exp2f(p[nt][r]);
      float s0 = (p[0][0] + p[0][1]) + (p[0][2] + p[0][3]);
      float s1 = (p[1][0] + p[1][1]) + (p[1][2] + p[1][3]);
      float s2 = (p[2][0] + p[2][1]) + (p[2][2] + p[2][3]);
      float s3 = (p[3][0] + p[3][1]) + (p[3][2] + p[3][3]);
      lrun[qf] += (s0 + s1) + (s2 + s3);
#pragma unroll
      for (int nt = 0; nt < 4; ++nt) {
        uint2 uu;
        uu.x = cvtpk(p[nt][0], p[nt][1]);
        uu.y = cvtpk(p[nt][2], p[nt][3]);
        *(uint2*)((char*)pw + (qf * 16 + lo) * 144 + nt * 32 + hi * 8) = uu;
      }
    }
    asm volatile("s_waitcnt lgkmcnt(0)" ::: "memory");
    short8 pa[2][2];
#pragma unroll
    for (int qf = 0; qf < 2; ++qf)
#pragma unroll
      for (int tc = 0; tc < 2; ++tc)
        pa[qf][tc] = *(const short8*)((const char*)pw + (qf * 16 + lo) * 144 + tc * 64 + hi * 16);
#pragma unroll
    for (int kf = 0; kf < 4; ++kf) {
#pragma unroll
      for (int tc = 0; tc < 2; ++tc) {
        const short8 vf = *(const short8*)(VsB + (kf * 16 + lo) * 128 + ((tc * 64 + hi * 16) ^ sw));
        zacc[0][kf] = MFMA16(vf, pa[0][tc], zacc[0][kf]);
        zacc[1][kf] = MFMA16(vf, pa[1][tc], zacc[1][kf]);
      }
    }
  }

  if (mode == 0) {
    u16* zp = z + (size_t)(b * 2048 + q0w) * 1024 + h * 64;
#pragma unroll
    for (int qf = 0; qf < 2; ++qf) {
      float rs = lrun[qf];
      rs += __shfl_xor(rs, 16);
      rs += __shfl_xor(rs, 32);
      const float inv = 1.f / rs;
#pragma unroll
      for (int kf = 0; kf < 4; ++kf) {
        uint2 o;
        o.x = cvtpk(zacc[qf][kf][0] * inv, zacc[qf][kf][1] * inv);
        o.y = cvtpk(zacc[qf][kf][2] * inv, zacc[qf][kf][3] * inv);
        *(uint2*)(zp + (size_t)(qf * 16 + lo) * 1024 + kf * 16 + hi * 4) = o;
      }
    }
  } else {
    const int seg = mode - 1;
    const int ci = chunk - 16;
    const int idx2 = (bg * 16 + ci) * 2 + (w & 1);
    u16* zs = zscr + ((size_t)seg * 512 * 4096) + ((size_t)idx2 * 64 + (w >> 1) * 32) * 64;
    float* ls = lscr + (size_t)seg * 512 * 64 + (size_t)idx2 * 64 + (w >> 1) * 32;
#pragma unroll
    for (int qf = 0; qf < 2; ++qf) {
      float rs = lrun[qf];
      rs += __shfl_xor(rs, 16);
      rs += __shfl_xor(rs, 32);
      if (hi == 0) ls[qf * 16 + lo] = rs;
#pragma unroll
      for (int kf = 0; kf < 4; ++kf) {
        uint2 o;
        o.x = cvtpk(zacc[qf][kf][0], zacc[qf][kf][1]);
        o.y = cvtpk(zacc[qf][kf][2], zacc[qf][kf][3]);
        *(uint2*)(zs + (size_t)(qf * 16 + lo) * 64 + kf * 16 + hi * 4) = o;
      }
    }
  }
}

// Combine: z[rows of chunks 16..31] = (z0+z1) / (l0+l1)
__global__ __launch_bounds__(256) void attn_combine(const u16* __restrict__ zscr,
    const float* __restrict__ lscr, u16* __restrict__ z)
{
  const int bgci = blockIdx.x;
  const int bg = bgci >> 4, ci = bgci & 15;
  const int b = bg >> 3, g = bg & 7, chunk = 16 + ci;
  const int tid = threadIdx.x;
#pragma unroll
  for (int j = 0; j < 4; ++j) {
    const int v = tid + j * 256;
    const int k8 = v & 7, row = (v >> 3) & 63, hh = v >> 9;
    const size_t base = ((size_t)(bgci * 2 + hh) * 64 + row) * 64 + k8 * 8;
    const short8 z0 = *(const short8*)(zscr + base);
    const short8 z1 = *(const short8*)(zscr + (size_t)512 * 4096 + base);
    const size_t lidx = (size_t)(bgci * 2 + hh) * 64 + row;
    const float inv = 1.f / (lscr[lidx] + lscr[(size_t)512 * 64 + lidx]);
    float a[8];
#pragma unroll
    for (int e = 0; e < 8; ++e)
      a[e] = (bf2f((u16)z0[e]) + bf2f((u16)z1[e])) * inv;
    uint4 o;
    o.x = cvtpk(a[0], a[1]);
    o.y = cvtpk(a[2], a[3]);
    o.z = cvtpk(a[4], a[5]);
    o.w = cvtpk(a[6], a[7]);
    *(uint4*)(z + ((size_t)(b * 2048 + chunk * 64 + row)) * 1024 + (g * 2 + hh) * 64 + k8 * 8) = o;
  }
}

// ---------------------------------------------------------------------------

extern "C" void kernel_launch(void* const* d_in, const int* in_sizes, int n_in,
                              void* d_out, int out_size, void* d_ws, size_t ws_size,
                              hipStream_t stream)
{
  (void)in_sizes; (void)n_in; (void)out_size; (void)ws_size;
  const float* x      = (const float*)d_in[0];
  const float* ln1_w  = (const float*)d_in[1];
  const float* ln1_b  = (const float*)d_in[2];
  const float* W_Q    = (const float*)d_in[3];
  const float* W_K    = (const float*)d_in[4];
  const float* W_V    = (const float*)d_in[5];
  const float* W_out  = (const float*)d_in[6];
  const float* b_out  = (const float*)d_in[7];
  const float* ln2_w  = (const float*)d_in[8];
  const float* ln2_b  = (const float*)d_in[9];
  const float* mlp1_w = (const float*)d_in[10];
  const float* mlp1_b = (const float*)d_in[11];
  const float* mlp2_w = (const float*)d_in[12];
  const float* mlp2_b = (const float*)d_in[13];
  float* out = (float*)d_out;

  char* ws = (char*)d_ws;
  u16*   wqkv_t = (u16*)(ws + 0);           // [2048][1024] bf16   4 MB
  u16*   wout_t = (u16*)(ws + 4194304);     // [1024][1024] bf16   2 MB
  u16*   w1     = (u16*)(ws + 6291456);     // [4096][1024] bf16   8 MB
  u16*   w2     = (u16*)(ws + 14680064);    // [1024][4096] bf16   8 MB
  u16*   normed = (u16*)(ws + 23068672);    // [4096][1024] bf16   8 MB (lscr during attn)
  float* post   = (float*)(ws + 31457280);  // [4096][1024] f32   16 MB (zscr during attn)
  u16*   qkv    = (u16*)(ws + 48234496);    // [4096][2048] bf16  16 MB
  u16*   vtb    = (u16*)(ws + 65011712);    // [16][64][2048] bf16 4 MB
  u16*   zb     = (u16*)(ws + 69206016);    // [4096][1024] bf16   8 MB
  u16*   hbuf   = (u16*)(ws + 48234496);    // [4096][4096] bf16  32 MB (reuses qkv/vt/z)
  u16*   zscr   = (u16*)(ws + 31457280);    // 8.4 MB partial z (inside post region)
  float* lscr   = (float*)(ws + 23068672);  // 262 KB partial l (inside normed region)

  prep_wqkv<<<dim3(64, 32), 256, 0, stream>>>(W_Q, W_K, W_V, wqkv_t);
  prep_wout<<<dim3(32, 32), 256, 0, stream>>>(W_out, wout_t);
  convert_bf16<<<4096, 256, 0, stream>>>((const float4*)mlp1_w, w1, 1048576);
  convert_bf16<<<4096, 256, 0, stream>>>((const float4*)mlp2_w, w2, 1048576);

  ln_bf16<<<4096, 256, 0, stream>>>(x, ln1_w, ln1_b, normed);
  gemm_bt<3><<<dim3(32, 16), 256, 0, stream>>>(normed, wqkv_t, qkv, nullptr, nullptr, 4096, 2048, 1024);
  vt_transpose<<<dim3(64, 2, 16), 256, 0, stream>>>(qkv, vtb);
  attn_fwd<<<dim3(48, 16), 256, 0, stream>>>(qkv, vtb, zb, zscr, lscr);
  attn_combine<<<256, 256, 0, stream>>>(zscr, lscr, zb);
  gemm_n64<1><<<dim3(32, 16), 256, 0, stream>>>(zb, wout_t, post, b_out, x, 4096, 1024, 1024);
  ln_bf16<<<4096, 256, 0, stream>>>(post, ln2_w, ln2_b, normed);
  gemm256<2><<<dim3(16, 16), 512, 0, stream>>>(normed, w1, hbuf, mlp1_b, nullptr, 4096, 4096, 1024);
  gemm_n64<1><<<dim3(32, 16), 256, 0, stream>>>(hbuf, w2, out, mlp2_b, post, 4096, 1024, 4096);
}

// Round 18
// 241.867 us; speedup vs baseline: 1.0749x; 1.0283x over previous
//
#include <hip/hip_runtime.h>
#include <cstdint>
#include <cstddef>

typedef __attribute__((ext_vector_type(8))) short short8;
typedef __attribute__((ext_vector_type(4))) float f32x4;
typedef unsigned short u16;

#define MFMA16(a, b, c) __builtin_amdgcn_mfma_f32_16x16x32_bf16((a), (b), (c), 0, 0, 0)
#define SCL2 0.18033688011112042f   /* 0.125 * log2(e) */

__device__ __forceinline__ u16 f2bf(float f) {
  union { float f; unsigned u; } c; c.f = f;
  unsigned r = c.u + 0x7fffu + ((c.u >> 16) & 1u);
  return (u16)(r >> 16);
}

__device__ __forceinline__ float bf2f(u16 x) {
  union { unsigned u; float f; } c; c.u = ((unsigned)x) << 16;
  return c.f;
}

__device__ __forceinline__ unsigned cvtpk(float a, float b) {
  unsigned r;
  asm("v_cvt_pk_bf16_f32 %0, %1, %2" : "=v"(r) : "v"(a), "v"(b));
  return r;
}

// ---------------------------------------------------------------------------
// Weight prep kernels (run every call; stateless)
// ---------------------------------------------------------------------------

__global__ __launch_bounds__(256) void prep_wqkv(const float* __restrict__ wq,
    const float* __restrict__ wk, const float* __restrict__ wv, u16* __restrict__ outp)
{
  __shared__ float t[32][33];
  const int tx = threadIdx.x & 31, ty = threadIdx.x >> 5;
  const int n0 = blockIdx.x * 32, d0 = blockIdx.y * 32;
  const float* src; int stride, nc;
  if (n0 < 1024)      { src = wq; stride = 1024; nc = n0; }
  else if (n0 < 1536) { src = wk; stride = 512;  nc = n0 - 1024; }
  else                { src = wv; stride = 512;  nc = n0 - 1536; }
#pragma unroll
  for (int i = 0; i < 32; i += 8)
    t[ty + i][tx] = src[(size_t)(d0 + ty + i) * stride + nc + tx];
  __syncthreads();
#pragma unroll
  for (int i = 0; i < 32; i += 8)
    outp[(size_t)(n0 + ty + i) * 1024 + d0 + tx] = f2bf(t[tx][ty + i]);
}

__global__ __launch_bounds__(256) void prep_wout(const float* __restrict__ wo, u16* __restrict__ outp)
{
  __shared__ float t[32][33];
  const int tx = threadIdx.x & 31, ty = threadIdx.x >> 5;
  const int d0 = blockIdx.x * 32, c0 = blockIdx.y * 32;
#pragma unroll
  for (int i = 0; i < 32; i += 8) {
    int c = c0 + ty + i;
    t[ty + i][tx] = wo[(size_t)(c & 63) * 16384 + (size_t)(c >> 6) * 1024 + d0 + tx];
  }
  __syncthreads();
#pragma unroll
  for (int i = 0; i < 32; i += 8)
    outp[(size_t)(d0 + ty + i) * 1024 + c0 + tx] = f2bf(t[tx][ty + i]);
}

__global__ void convert_bf16(const float4* __restrict__ in, u16* __restrict__ out, int n4) {
  int i = blockIdx.x * 256 + threadIdx.x;
  if (i >= n4) return;
  float4 v = in[i];
  ushort4 o; o.x = f2bf(v.x); o.y = f2bf(v.y); o.z = f2bf(v.z); o.w = f2bf(v.w);
  ((ushort4*)out)[i] = o;
}

// Vt[b][g][k][t] from qkv cols 1536+g*64+k
__global__ __launch_bounds__(256) void vt_transpose(const u16* __restrict__ qkv, u16* __restrict__ vtp)
{
  __shared__ u16 t[32][33];
  const int tx = threadIdx.x & 31, ty = threadIdx.x >> 5;
  const int t0 = blockIdx.x * 32, k0 = blockIdx.y * 32;
  const int bg = blockIdx.z, b = bg >> 3, g = bg & 7;
#pragma unroll
  for (int i = 0; i < 32; i += 8)
    t[ty + i][tx] = qkv[(size_t)(b * 2048 + t0 + ty + i) * 2048 + 1536 + g * 64 + k0 + tx];
  __syncthreads();
#pragma unroll
  for (int i = 0; i < 32; i += 8)
    vtp[(size_t)(bg * 64 + k0 + ty + i) * 2048 + t0 + tx] = t[tx][ty + i];
}

// ---------------------------------------------------------------------------
// LayerNorm (fp32 in -> bf16 out)
// ---------------------------------------------------------------------------
__global__ __launch_bounds__(256) void ln_bf16(const float* __restrict__ x,
    const float* __restrict__ w, const float* __restrict__ b, u16* __restrict__ out)
{
  const int row = blockIdx.x, tid = threadIdx.x;
  const float4 v = ((const float4*)(x + (size_t)row * 1024))[tid];
  float s = v.x + v.y + v.z + v.w;
  float s2 = v.x * v.x + v.y * v.y + v.z * v.z + v.w * v.w;
#pragma unroll
  for (int m = 32; m >= 1; m >>= 1) { s += __shfl_xor(s, m); s2 += __shfl_xor(s2, m); }
  __shared__ float red[8];
  if ((tid & 63) == 0) { red[tid >> 6] = s; red[4 + (tid >> 6)] = s2; }
  __syncthreads();
  s  = red[0] + red[1] + red[2] + red[3];
  s2 = red[4] + red[5] + red[6] + red[7];
  const float mu = s * (1.f / 1024.f);
  const float inv = rsqrtf(s2 * (1.f / 1024.f) - mu * mu + 1e-5f);
  const float4 wv = ((const float4*)w)[tid];
  const float4 bv = ((const float4*)b)[tid];
  ushort4 o;
  o.x = f2bf((v.x - mu) * inv * wv.x + bv.x);
  o.y = f2bf((v.y - mu) * inv * wv.y + bv.y);
  o.z = f2bf((v.z - mu) * inv * wv.z + bv.z);
  o.w = f2bf((v.w - mu) * inv * wv.w + bv.w);
  ((ushort4*)out)[(size_t)row * 256 + tid] = o;
}

// ---------------------------------------------------------------------------
// GEMM 128x128 v5: counted-vmcnt pipeline; K = per-split loop extent,
// Ks = row stride, blockIdx.z selects K-split (A/Bt advanced by z*K).
// EPI: 3 bf16, cols<1024 pre-scaled by SCL2 (QKV) ;
//      4 bf16 partial (z=0 -> Cout, z=1 -> Cout2)  (MLP2 split-K)
// 64x64 per-wave tile => 2 MFMA per KB of LDS reads (best reuse ratio).
// ---------------------------------------------------------------------------
#define BM 128
#define BN 128
#define BK 32

template<int EPI>
__global__ __launch_bounds__(256, 2) void gemm_bt(
    const u16* __restrict__ A, const u16* __restrict__ Bt,
    void* __restrict__ Cout, void* __restrict__ Cout2,
    const float* __restrict__ bias, const float* __restrict__ resid,
    int M, int N, int K, int Ks)
{
  __shared__ u16 As[4][BM * BK];
  __shared__ u16 Bs[4][BN * BK];
  const int tid = threadIdx.x;
  const int w = tid >> 6, lane = tid & 63;
  const int lo = lane & 15, hi = lane >> 4;
  const int mBase = blockIdx.x * BM, nBase = blockIdx.y * BN;
  const int wr = (w >> 1) * 64, wc = (w & 1) * 64;
  A += (size_t)blockIdx.z * K;
  Bt += (size_t)blockIdx.z * K;

  const f32x4 vzero = {0.f, 0.f, 0.f, 0.f};
  f32x4 acc[4][4];
#pragma unroll
  for (int i = 0; i < 4; ++i)
#pragma unroll
    for (int j = 0; j < 4; ++j) acc[i][j] = vzero;

  const int base0 = w * 2048 + lane * 16;
  int srow[2], skb[2];
#pragma unroll
  for (int c = 0; c < 2; ++c) {
    const int off = base0 + c * 1024;
    srow[c] = off >> 6;
    skb[c] = ((off & 63) ^ ((srow[c] & 3) << 4)) >> 1;
  }

  const int NT = K >> 5;

  auto stage = [&](int kt) {
    const int slot = kt & 3;
    const int k0 = kt * BK;
#pragma unroll
    for (int c = 0; c < 2; ++c) {
      const u16* ga = A  + (size_t)(mBase + srow[c]) * Ks + k0 + skb[c];
      const u16* gb = Bt + (size_t)(nBase + srow[c]) * Ks + k0 + skb[c];
      __builtin_amdgcn_global_load_lds((const __attribute__((address_space(1))) void*)ga,
          (__attribute__((address_space(3))) void*)((char*)&As[slot][0] + w * 2048 + c * 1024), 16, 0, 0);
      __builtin_amdgcn_global_load_lds((const __attribute__((address_space(1))) void*)gb,
          (__attribute__((address_space(3))) void*)((char*)&Bs[slot][0] + w * 2048 + c * 1024), 16, 0, 0);
    }
  };

  stage(0);
  stage(1);

  for (int kt = 0; kt < NT; ++kt) {
    if (kt + 2 < NT) {
      stage(kt + 2);
      asm volatile("s_waitcnt vmcnt(8)" ::: "memory");
    } else if (kt + 1 < NT) {
      asm volatile("s_waitcnt vmcnt(4)" ::: "memory");
    } else {
      asm volatile("s_waitcnt vmcnt(0)" ::: "memory");
    }
    __builtin_amdgcn_s_barrier();
    __builtin_amdgcn_sched_barrier(0);

    const int slot = kt & 3;
    short8 af[4], bf[4];
#pragma unroll
    for (int i = 0; i < 4; ++i) {
      const int ra = wr + i * 16 + lo;
      const int rb = wc + i * 16 + lo;
      af[i] = *(const short8*)((const char*)&As[slot][0] + ra * 64 + ((hi * 16) ^ ((ra & 3) << 4)));
      bf[i] = *(const short8*)((const char*)&Bs[slot][0] + rb * 64 + ((hi * 16) ^ ((rb & 3) << 4)));
    }
    __builtin_amdgcn_s_setprio(1);
#pragma unroll
    for (int i = 0; i < 4; ++i)
#pragma unroll
      for (int j = 0; j < 4; ++j)
        acc[i][j] = MFMA16(af[i], bf[j], acc[i][j]);
    __builtin_amdgcn_s_setprio(0);
  }

  void* sel = (EPI == 4 && blockIdx.z) ? Cout2 : Cout;
#pragma unroll
  for (int i = 0; i < 4; ++i) {
#pragma unroll
    for (int j = 0; j < 4; ++j) {
#pragma unroll
      for (int r = 0; r < 4; ++r) {
        const int row = mBase + wr + i * 16 + hi * 4 + r;
        const int col = nBase + wc + j * 16 + lo;
        float v = acc[i][j][r];
        if (EPI == 3 && col < 1024) v *= SCL2;
        ((u16*)sel)[(size_t)row * N + col] = f2bf(v);
      }
    }
  }
}

// MLP2 split-K combine: out = p0 + p1 + bias + resid  (4096x1024 fp32)
__global__ __launch_bounds__(256) void mlp2_combine(const u16* __restrict__ p0,
    const u16* __restrict__ p1, const float* __restrict__ bias,
    const float* __restrict__ resid, float* __restrict__ out)
{
  const int tid = threadIdx.x;
  const int c0 = tid * 4;
  const float4 bv = *(const float4*)(bias + c0);
#pragma unroll
  for (int rr = 0; rr < 4; ++rr) {
    const int row = blockIdx.x * 4 + rr;
    const size_t off = (size_t)row * 1024 + c0;
    const ushort4 a = *(const ushort4*)(p0 + off);
    const ushort4 b = *(const ushort4*)(p1 + off);
    const float4 rv = *(const float4*)(resid + off);
    float4 o;
    o.x = bf2f(a.x) + bf2f(b.x) + bv.x + rv.x;
    o.y = bf2f(a.y) + bf2f(b.y) + bv.y + rv.y;
    o.z = bf2f(a.z) + bf2f(b.z) + bv.z + rv.z;
    o.w = bf2f(a.w) + bf2f(b.w) + bv.w + rv.w;
    *(float4*)(out + off) = o;
  }
}

// ---------------------------------------------------------------------------
// GEMM 128x64 v2 (out-proj): counted-vmcnt ring + swizzle. +bias+resid -> fp32
// ---------------------------------------------------------------------------
__global__ __launch_bounds__(256, 3) void gemm_n64(
    const u16* __restrict__ A, const u16* __restrict__ Bt, void* __restrict__ Cout,
    const float* __restrict__ bias, const float* __restrict__ resid,
    int M, int N, int K)
{
  __shared__ u16 As[4][128 * 32];
  __shared__ u16 Bs[4][64 * 32];
  const int tid = threadIdx.x;
  const int w = tid >> 6, lane = tid & 63;
  const int lo = lane & 15, hi = lane >> 4;
  const int mBase = blockIdx.x * 128, nBase = blockIdx.y * 64;
  const int wr = (w >> 1) * 64, wc = (w & 1) * 32;

  const f32x4 vzero = {0.f, 0.f, 0.f, 0.f};
  f32x4 acc[4][2];
#pragma unroll
  for (int i = 0; i < 4; ++i)
#pragma unroll
    for (int j = 0; j < 2; ++j) acc[i][j] = vzero;

  int arow[2], akb[2];
#pragma unroll
  for (int c = 0; c < 2; ++c) {
    const int off = tid * 16 + c * 4096;
    arow[c] = off >> 6;
    akb[c] = ((off & 63) ^ ((arow[c] & 3) << 4)) >> 1;
  }
  const int boff = tid * 16;
  const int brow = boff >> 6;
  const int bkb = ((boff & 63) ^ ((brow & 3) << 4)) >> 1;

  const int NT = K >> 5;

  auto stage = [&](int kt) {
    const int slot = kt & 3;
    const int k0 = kt * 32;
#pragma unroll
    for (int c = 0; c < 2; ++c) {
      const u16* ga = A + (size_t)(mBase + arow[c]) * K + k0 + akb[c];
      __builtin_amdgcn_global_load_lds((const __attribute__((address_space(1))) void*)ga,
          (__attribute__((address_space(3))) void*)((char*)&As[slot][0] + tid * 16 + c * 4096), 16, 0, 0);
    }
    const u16* gb = Bt + (size_t)(nBase + brow) * K + k0 + bkb;
    __builtin_amdgcn_global_load_lds((const __attribute__((address_space(1))) void*)gb,
        (__attribute__((address_space(3))) void*)((char*)&Bs[slot][0] + tid * 16), 16, 0, 0);
  };

  stage(0);
  stage(1);

  for (int kt = 0; kt < NT; ++kt) {
    if (kt + 2 < NT) {
      stage(kt + 2);
      asm volatile("s_waitcnt vmcnt(6)" ::: "memory");
    } else if (kt + 1 < NT) {
      asm volatile("s_waitcnt vmcnt(3)" ::: "memory");
    } else {
      asm volatile("s_waitcnt vmcnt(0)" ::: "memory");
    }
    __builtin_amdgcn_s_barrier();
    __builtin_amdgcn_sched_barrier(0);

    const int slot = kt & 3;
    short8 af[4], bf[2];
#pragma unroll
    for (int i = 0; i < 4; ++i) {
      const int ra = wr + i * 16 + lo;
      af[i] = *(const short8*)((const char*)&As[slot][0] + ra * 64 + ((hi * 16) ^ ((ra & 3) << 4)));
    }
#pragma unroll
    for (int j = 0; j < 2; ++j) {
      const int rb = wc + j * 16 + lo;
      bf[j] = *(const short8*)((const char*)&Bs[slot][0] + rb * 64 + ((hi * 16) ^ ((rb & 3) << 4)));
    }
    __builtin_amdgcn_s_setprio(1);
#pragma unroll
    for (int i = 0; i < 4; ++i)
#pragma unroll
      for (int j = 0; j < 2; ++j)
        acc[i][j] = MFMA16(af[i], bf[j], acc[i][j]);
    __builtin_amdgcn_s_setprio(0);
  }

#pragma unroll
  for (int i = 0; i < 4; ++i) {
#pragma unroll
    for (int j = 0; j < 2; ++j) {
#pragma unroll
      for (int r = 0; r < 4; ++r) {
        const int row = mBase + wr + i * 16 + hi * 4 + r;
        const int col = nBase + wc + j * 16 + lo;
        float v = acc[i][j][r];
        v += bias[col];
        v += resid[(size_t)row * N + col];
        ((float*)Cout)[(size_t)row * N + col] = v;
      }
    }
  }
}

// ---------------------------------------------------------------------------
// GEMM 256x256 v2 (flat schedule, round-9 verified) — unchanged
// ---------------------------------------------------------------------------
template<int EPI>
__global__ __launch_bounds__(512, 2) void gemm256(
    const u16* __restrict__ A, const u16* __restrict__ Bt, void* __restrict__ Cout,
    const float* __restrict__ bias, const float* __restrict__ resid,
    int M, int N, int K)
{
  __shared__ u16 lds8[2][2][2][8192];
  const int tid = threadIdx.x;
  const int lane = tid & 63, lo = lane & 15, hi = lane >> 4;
  const int wid = tid >> 6, wr = wid >> 2, wc = wid & 3;
  const int mBase = blockIdx.x * 256, nBase = blockIdx.y * 256;
  const int sw = (lo & 7) << 4;

  const f32x4 vzero = {0.f, 0.f, 0.f, 0.f};
  f32x4 acc[8][4];
#pragma unroll
  for (int i = 0; i < 8; ++i)
#pragma unroll
    for (int j = 0; j < 4; ++j) acc[i][j] = vzero;

  int srow[2], scol[2];
#pragma unroll
  for (int c = 0; c < 2; ++c) {
    const int p = c * 8192 + tid * 16;
    const int r = p >> 7, bb = p & 127;
    srow[c] = r;
    scol[c] = (bb ^ ((r & 7) << 4)) >> 1;
  }

  const int NT = K >> 6;

#pragma unroll
  for (int mat = 0; mat < 2; ++mat)
#pragma unroll
    for (int half = 0; half < 2; ++half)
#pragma unroll
      for (int c = 0; c < 2; ++c) {
        const u16* g = (mat == 0)
          ? A  + (size_t)(mBase + half * 128 + srow[c]) * K + scol[c]
          : Bt + (size_t)(nBase + half * 128 + srow[c]) * K + scol[c];
        __builtin_amdgcn_global_load_lds((const __attribute__((address_space(1))) void*)g,
            (__attribute__((address_space(3))) void*)(&lds8[0][mat][half][c * 4096 + tid * 8]), 16, 0, 0);
      }
  asm volatile("s_waitcnt vmcnt(0)" ::: "memory");
  asm volatile("s_barrier" ::: "memory");

  for (int kt = 0; kt < NT; ++kt) {
    const int cur = kt & 1;
    const char* baseA = (const char*)&lds8[cur][0][wr][0];
    const char* baseB = (const char*)&lds8[cur][1][wc >> 1][0];
    const int rBB = (wc & 1) * 64;

    short8 bfr[4][2], afr[4][2];
#pragma unroll
    for (int nf = 0; nf < 4; ++nf)
#pragma unroll
      for (int ks = 0; ks < 2; ++ks)
        bfr[nf][ks] = *(const short8*)(baseB + (rBB + nf * 16 + lo) * 128 + ((ks * 64 + hi * 16) ^ sw));
#pragma unroll
    for (int mf = 0; mf < 4; ++mf)
#pragma unroll
      for (int ks = 0; ks < 2; ++ks)
        afr[mf][ks] = *(const short8*)(baseA + ((mf * 16 + lo) * 128 + ((ks * 64 + hi * 16) ^ sw)));

    if (kt + 1 < NT) {
      const int ko = (kt + 1) * 64;
#pragma unroll
      for (int mat = 0; mat < 2; ++mat)
#pragma unroll
        for (int half = 0; half < 2; ++half)
#pragma unroll
          for (int c = 0; c < 2; ++c) {
            const u16* g = (mat == 0)
              ? A  + (size_t)(mBase + half * 128 + srow[c]) * K + ko + scol[c]
              : Bt + (size_t)(nBase + half * 128 + srow[c]) * K + ko + scol[c];
            __builtin_amdgcn_global_load_lds((const __attribute__((address_space(1))) void*)g,
                (__attribute__((address_space(3))) void*)(&lds8[cur ^ 1][mat][half][c * 4096 + tid * 8]), 16, 0, 0);
          }
    }

    __builtin_amdgcn_s_setprio(1);
#pragma unroll
    for (int mf = 0; mf < 4; ++mf)
#pragma unroll
      for (int nf = 0; nf < 4; ++nf)
#pragma unroll
        for (int ks = 0; ks < 2; ++ks)
          acc[mf][nf] = MFMA16(afr[mf][ks], bfr[nf][ks], acc[mf][nf]);
    __builtin_amdgcn_s_setprio(0);

#pragma unroll
    for (int mf = 0; mf < 4; ++mf)
#pragma unroll
      for (int ks = 0; ks < 2; ++ks)
        afr[mf][ks] = *(const short8*)(baseA + (((mf + 4) * 16 + lo) * 128 + ((ks * 64 + hi * 16) ^ sw)));

    __builtin_amdgcn_s_setprio(1);
#pragma unroll
    for (int mf = 0; mf < 4; ++mf)
#pragma unroll
      for (int nf = 0; nf < 4; ++nf)
#pragma unroll
        for (int ks = 0; ks < 2; ++ks)
          acc[mf + 4][nf] = MFMA16(afr[mf][ks], bfr[nf][ks], acc[mf + 4][nf]);
    __builtin_amdgcn_s_setprio(0);

    asm volatile("s_waitcnt vmcnt(0)" ::: "memory");
    asm volatile("s_barrier" ::: "memory");
  }

#pragma unroll
  for (int mf = 0; mf < 8; ++mf) {
#pragma unroll
    for (int nf = 0; nf < 4; ++nf) {
#pragma unroll
      for (int r = 0; r < 4; ++r) {
        const int row = mBase + wr * 128 + mf * 16 + hi * 4 + r;
        const int col = nBase + wc * 64 + nf * 16 + lo;
        float v = acc[mf][nf][r];
        if (EPI != 0) v += bias[col];
        if (EPI == 1) v += resid[(size_t)row * N + col];
        if (EPI == 2) v = 0.5f * v * (1.f + erff(v * 0.70710678118f));
        if (EPI == 1) ((float*)Cout)[(size_t)row * N + col] = v;
        else          ((u16*)Cout)[(size_t)row * N + col] = f2bf(v);
      }
    }
  }
}

// ---------------------------------------------------------------------------
// Flash attention v9 (round-14 verified): split-T + fixed-max softmax
// ---------------------------------------------------------------------------
__global__ __launch_bounds__(256) void attn_fwd(const u16* __restrict__ qkv,
    const u16* __restrict__ vt, u16* __restrict__ z,
    u16* __restrict__ zscr, float* __restrict__ lscr)
{
  __shared__ u16 Ks[2][64 * 64];
  __shared__ u16 Vs[2][64 * 64];
  __shared__ u16 Pl[4][32 * 72];
  const int tid = threadIdx.x;
  const int w = tid >> 6, lane = tid & 63, lo = lane & 15, hi = lane >> 4;
  const int bx = blockIdx.x;
  int chunk, itBeg, itEnd, mode;
  if (bx < 16)      { chunk = bx;      itBeg = 0;  itEnd = chunk + 1; mode = 0; }
  else if (bx < 32) { chunk = bx;      itBeg = 0;  itEnd = 16;        mode = 1; }
  else              { chunk = bx - 16; itBeg = 16; itEnd = chunk + 1; mode = 2; }
  const int bg = blockIdx.y, b = bg >> 3, g = bg & 7;
  const int h = (g << 1) | (w & 1);
  const int q0w = chunk * 64 + (w >> 1) * 32;
  const int sw = (lo & 7) << 4;

  short8 qA[2][2];
#pragma unroll
  for (int qf = 0; qf < 2; ++qf)
#pragma unroll
    for (int half = 0; half < 2; ++half)
      qA[qf][half] = *(const short8*)(qkv +
          (size_t)(b * 2048 + q0w + qf * 16 + lo) * 2048 + h * 64 + half * 32 + hi * 8);

  const f32x4 vzero = {0.f, 0.f, 0.f, 0.f};
  f32x4 zacc[2][4];
#pragma unroll
  for (int qf = 0; qf < 2; ++qf)
#pragma unroll
    for (int kf = 0; kf < 4; ++kf) zacc[qf][kf] = vzero;
  float lrun[2] = {0.f, 0.f};

  const u16* kbase = qkv + (size_t)b * 2048 * 2048 + 1024 + g * 64;
  const u16* vbase = vt + (size_t)(b * 8 + g) * 64 * 2048;

  int srow[2], scol[2];
#pragma unroll
  for (int c = 0; c < 2; ++c) {
    const int p = tid * 16 + c * 4096;
    const int r = p >> 7, bb = p & 127;
    srow[c] = r;
    scol[c] = (bb ^ ((r & 7) << 4)) >> 1;
  }

  u16* pw = &Pl[w][0];

  auto stageKV = [&](int it) {
    const int slot = it & 1;
    const int t0 = it * 64;
#pragma unroll
    for (int c = 0; c < 2; ++c) {
      __builtin_amdgcn_global_load_lds(
          (const __attribute__((address_space(1))) void*)(kbase + (size_t)(t0 + srow[c]) * 2048 + scol[c]),
          (__attribute__((address_space(3))) void*)((char*)&Ks[slot][0] + tid * 16 + c * 4096), 16, 0, 0);
      __builtin_amdgcn_global_load_lds(
          (const __attribute__((address_space(1))) void*)(vbase + (size_t)srow[c] * 2048 + t0 + scol[c]),
          (__attribute__((address_space(3))) void*)((char*)&Vs[slot][0] + tid * 16 + c * 4096), 16, 0, 0);
    }
  };

  stageKV(itBeg);

  for (int it = itBeg; it < itEnd; ++it) {
    asm volatile("s_waitcnt vmcnt(0)" ::: "memory");
    __builtin_amdgcn_s_barrier();
    __builtin_amdgcn_sched_barrier(0);
    if (it + 1 < itEnd) stageKV(it + 1);

    const int slot = it & 1;
    const int ts = it * 64;
    const char* KsB = (const char*)&Ks[slot][0];
    const char* VsB = (const char*)&Vs[slot][0];

    short8 kA[4][2];
#pragma unroll
    for (int nt = 0; nt < 4; ++nt)
#pragma unroll
      for (int half = 0; half < 2; ++half)
        kA[nt][half] = *(const short8*)(KsB + (nt * 16 + lo) * 128 + ((half * 64 + hi * 16) ^ sw));

#pragma unroll
    for (int qf = 0; qf < 2; ++qf) {
      f32x4 p[4];
#pragma unroll
      for (int nt = 0; nt < 4; ++nt) {
        f32x4 t = MFMA16(kA[nt][0], qA[qf][0], vzero);
        p[nt] = MFMA16(kA[nt][1], qA[qf][1], t);
      }
      const int qrow0 = q0w + qf * 16;
      if (ts + 63 > qrow0) {
        const int rel = qrow0 + lo - ts;
#pragma unroll
        for (int nt = 0; nt < 4; ++nt)
#pragma unroll
          for (int r = 0; r < 4; ++r)
            if (nt * 16 + hi * 4 + r > rel) p[nt][r] = -1e30f;
      }
#pragma unroll
      for (int nt = 0; nt < 4; ++nt)
#pragma unroll
        for (int r = 0; r < 4; ++r) p[nt][r] = exp2f(p[nt][r]);
      float s0 = (p[0][0] + p[0][1]) + (p[0][2] + p[0][3]);
      float s1 = (p[1][0] + p[1][1]) + (p[1][2] + p[1][3]);
      float s2 = (p[2][0] + p[2][1]) + (p[2][2] + p[2][3]);
      float s3 = (p[3][0] + p[3][1]) + (p[3][2] + p[3][3]);
      lrun[qf] += (s0 + s1) + (s2 + s3);
#pragma unroll
      for (int nt = 0; nt < 4; ++nt) {
        uint2 uu;
        uu.x = cvtpk(p[nt][0], p[nt][1]);
        uu.y = cvtpk(p[nt][2], p[nt][3]);
        *(uint2*)((char*)pw + (qf * 16 + lo) * 144 + nt * 32 + hi * 8) = uu;
      }
    }
    asm volatile("s_waitcnt lgkmcnt(0)" ::: "memory");
    short8 pa[2][2];
#pragma unroll
    for (int qf = 0; qf < 2; ++qf)
#pragma unroll
      for (int tc = 0; tc < 2; ++tc)
        pa[qf][tc] = *(const short8*)((const char*)pw + (qf * 16 + lo) * 144 + tc * 64 + hi * 16);
#pragma unroll
    for (int kf = 0; kf < 4; ++kf) {
#pragma unroll
      for (int tc = 0; tc < 2; ++tc) {
        const short8 vf = *(const short8*)(VsB + (kf * 16 + lo) * 128 + ((tc * 64 + hi * 16) ^ sw));
        zacc[0][kf] = MFMA16(vf, pa[0][tc], zacc[0][kf]);
        zacc[1][kf] = MFMA16(vf, pa[1][tc], zacc[1][kf]);
      }
    }
  }

  if (mode == 0) {
    u16* zp = z + (size_t)(b * 2048 + q0w) * 1024 + h * 64;
#pragma unroll
    for (int qf = 0; qf < 2; ++qf) {
      float rs = lrun[qf];
      rs += __shfl_xor(rs, 16);
      rs += __shfl_xor(rs, 32);
      const float inv = 1.f / rs;
#pragma unroll
      for (int kf = 0; kf < 4; ++kf) {
        uint2 o;
        o.x = cvtpk(zacc[qf][kf][0] * inv, zacc[qf][kf][1] * inv);
        o.y = cvtpk(zacc[qf][kf][2] * inv, zacc[qf][kf][3] * inv);
        *(uint2*)(zp + (size_t)(qf * 16 + lo) * 1024 + kf * 16 + hi * 4) = o;
      }
    }
  } else {
    const int seg = mode - 1;
    const int ci = chunk - 16;
    const int idx2 = (bg * 16 + ci) * 2 + (w & 1);
    u16* zs = zscr + ((size_t)seg * 512 * 4096) + ((size_t)idx2 * 64 + (w >> 1) * 32) * 64;
    float* ls = lscr + (size_t)seg * 512 * 64 + (size_t)idx2 * 64 + (w >> 1) * 32;
#pragma unroll
    for (int qf = 0; qf < 2; ++qf) {
      float rs = lrun[qf];
      rs += __shfl_xor(rs, 16);
      rs += __shfl_xor(rs, 32);
      if (hi == 0) ls[qf * 16 + lo] = rs;
#pragma unroll
      for (int kf = 0; kf < 4; ++kf) {
        uint2 o;
        o.x = cvtpk(zacc[qf][kf][0], zacc[qf][kf][1]);
        o.y = cvtpk(zacc[qf][kf][2], zacc[qf][kf][3]);
        *(uint2*)(zs + (size_t)(qf * 16 + lo) * 64 + kf * 16 + hi * 4) = o;
      }
    }
  }
}

// Combine: z[rows of chunks 16..31] = (z0+z1) / (l0+l1)
__global__ __launch_bounds__(256) void attn_combine(const u16* __restrict__ zscr,
    const float* __restrict__ lscr, u16* __restrict__ z)
{
  const int bgci = blockIdx.x;
  const int bg = bgci >> 4, ci = bgci & 15;
  const int b = bg >> 3, g = bg & 7, chunk = 16 + ci;
  const int tid = threadIdx.x;
#pragma unroll
  for (int j = 0; j < 4; ++j) {
    const int v = tid + j * 256;
    const int k8 = v & 7, row = (v >> 3) & 63, hh = v >> 9;
    const size_t base = ((size_t)(bgci * 2 + hh) * 64 + row) * 64 + k8 * 8;
    const short8 z0 = *(const short8*)(zscr + base);
    const short8 z1 = *(const short8*)(zscr + (size_t)512 * 4096 + base);
    const size_t lidx = (size_t)(bgci * 2 + hh) * 64 + row;
    const float inv = 1.f / (lscr[lidx] + lscr[(size_t)512 * 64 + lidx]);
    float a[8];
#pragma unroll
    for (int e = 0; e < 8; ++e)
      a[e] = (bf2f((u16)z0[e]) + bf2f((u16)z1[e])) * inv;
    uint4 o;
    o.x = cvtpk(a[0], a[1]);
    o.y = cvtpk(a[2], a[3]);
    o.z = cvtpk(a[4], a[5]);
    o.w = cvtpk(a[6], a[7]);
    *(uint4*)(z + ((size_t)(b * 2048 + chunk * 64 + row)) * 1024 + (g * 2 + hh) * 64 + k8 * 8) = o;
  }
}

// ---------------------------------------------------------------------------

extern "C" void kernel_launch(void* const* d_in, const int* in_sizes, int n_in,
                              void* d_out, int out_size, void* d_ws, size_t ws_size,
                              hipStream_t stream)
{
  (void)in_sizes; (void)n_in; (void)out_size; (void)ws_size;
  const float* x      = (const float*)d_in[0];
  const float* ln1_w  = (const float*)d_in[1];
  const float* ln1_b  = (const float*)d_in[2];
  const float* W_Q    = (const float*)d_in[3];
  const float* W_K    = (const float*)d_in[4];
  const float* W_V    = (const float*)d_in[5];
  const float* W_out  = (const float*)d_in[6];
  const float* b_out  = (const float*)d_in[7];
  const float* ln2_w  = (const float*)d_in[8];
  const float* ln2_b  = (const float*)d_in[9];
  const float* mlp1_w = (const float*)d_in[10];
  const float* mlp1_b = (const float*)d_in[11];
  const float* mlp2_w = (const float*)d_in[12];
  const float* mlp2_b = (const float*)d_in[13];
  float* out = (float*)d_out;

  char* ws = (char*)d_ws;
  u16*   wqkv_t = (u16*)(ws + 0);           // [2048][1024] bf16   4 MB
  u16*   wout_t = (u16*)(ws + 4194304);     // [1024][1024] bf16   2 MB
  u16*   w1     = (u16*)(ws + 6291456);     // [4096][1024] bf16   8 MB
  u16*   w2     = (u16*)(ws + 14680064);    // [1024][4096] bf16   8 MB
  u16*   normed = (u16*)(ws + 23068672);    // [4096][1024] bf16   8 MB (lscr; mlp2 p1)
  float* post   = (float*)(ws + 31457280);  // [4096][1024] f32   16 MB (zscr during attn)
  u16*   qkv    = (u16*)(ws + 48234496);    // [4096][2048] bf16  16 MB
  u16*   vtb    = (u16*)(ws + 65011712);    // [16][64][2048] bf16 4 MB
  u16*   zb     = (u16*)(ws + 69206016);    // [4096][1024] bf16   8 MB
  u16*   hbuf   = (u16*)(ws + 48234496);    // [4096][4096] bf16  32 MB (reuses qkv/vt/z)
  u16*   zscr   = (u16*)(ws + 31457280);    // 8.4 MB partial z (inside post region)
  float* lscr   = (float*)(ws + 23068672);  // 262 KB partial l (inside normed region)
  u16*   mp0    = (u16*)(ws + 0);           // MLP2 K-half-0 partial, 8 MB (wqkv_t/wout_t/w1[0:2MB] dead)
  u16*   mp1    = (u16*)(ws + 23068672);    // MLP2 K-half-1 partial, 8 MB (normed dead)

  prep_wqkv<<<dim3(64, 32), 256, 0, stream>>>(W_Q, W_K, W_V, wqkv_t);
  prep_wout<<<dim3(32, 32), 256, 0, stream>>>(W_out, wout_t);
  convert_bf16<<<4096, 256, 0, stream>>>((const float4*)mlp1_w, w1, 1048576);
  convert_bf16<<<4096, 256, 0, stream>>>((const float4*)mlp2_w, w2, 1048576);

  ln_bf16<<<4096, 256, 0, stream>>>(x, ln1_w, ln1_b, normed);
  gemm_bt<3><<<dim3(32, 16), 256, 0, stream>>>(normed, wqkv_t, qkv, nullptr, nullptr, nullptr, 4096, 2048, 1024, 1024);
  vt_transpose<<<dim3(64, 2, 16), 256, 0, stream>>>(qkv, vtb);
  attn_fwd<<<dim3(48, 16), 256, 0, stream>>>(qkv, vtb, zb, zscr, lscr);
  attn_combine<<<256, 256, 0, stream>>>(zscr, lscr, zb);
  gemm_n64<<<dim3(32, 16), 256, 0, stream>>>(zb, wout_t, post, b_out, x, 4096, 1024, 1024);
  ln_bf16<<<4096, 256, 0, stream>>>(post, ln2_w, ln2_b, normed);
  gemm256<2><<<dim3(16, 16), 512, 0, stream>>>(normed, w1, hbuf, mlp1_b, nullptr, 4096, 4096, 1024);
  gemm_bt<4><<<dim3(32, 8, 2), 256, 0, stream>>>(hbuf, w2, mp0, mp1, nullptr, nullptr, 4096, 1024, 2048, 4096);
  mlp2_combine<<<1024, 256, 0, stream>>>(mp0, mp1, mlp2_b, post, out);
}